// Round 18
// baseline (11014.050 us; speedup 1.0000x reference)
//
#include <hip/hip_runtime.h>
#include <hip/hip_bf16.h>
#include <math.h>

#define B 64
#define T 19
#define S 80
#define V 32000
#define E 256
#define U 1024
#define U3 (3*U)        // 3072
#define KXM (E+U)       // 1280
#define NBLK 768        // mega-kernel grid (3 blocks/CU x 256 CUs)

typedef unsigned short ushortT;
typedef __attribute__((ext_vector_type(8))) __bf16 bf16x8;
typedef __attribute__((ext_vector_type(4))) float f32x4;

__device__ __forceinline__ ushortT f2bf(float f) {
    unsigned int u = __float_as_uint(f);
    u = (u + 0x7FFF + ((u >> 16) & 1)) >> 16;   // RNE
    return (ushortT)u;
}
__device__ __forceinline__ float bf2f(ushortT u) {
    return __uint_as_float(((unsigned int)u) << 16);
}
__device__ __forceinline__ void split3(float v, ushortT& hi, ushortT& mid, ushortT& lo) {
    hi = f2bf(v);
    float r1 = v - bf2f(hi);
    mid = f2bf(r1);
    float r2 = r1 - bf2f(mid);
    lo = f2bf(r2);
}

// ---------------------------------------------------------------------------
// Merged pre-split weight pack: 5 matrices in one launch.
// ---------------------------------------------------------------------------
struct PackJob { const float* W; ushortT* Wp; int N; int K; int blk0; };

__global__ __launch_bounds__(256) void pack_w3_all(
    PackJob j0, PackJob j1, PackJob j2, PackJob j3, PackJob j4)
{
    int bid = blockIdx.x;
    PackJob J = j4;
    if (bid < j1.blk0) J = j0;
    else if (bid < j2.blk0) J = j1;
    else if (bid < j3.blk0) J = j2;
    else if (bid < j4.blk0) J = j3;

    int idx = (bid - J.blk0) * 256 + threadIdx.x;
    int lane = idx & 63;
    int t = idx >> 6;
    int KC = J.K >> 5;
    int ntile = t / KC, kc = t - ntile * KC;
    int col = ntile * 16 + (lane & 15);
    int krow = kc * 32 + (lane >> 4) * 8;
    ushortT hi[8], mi[8], lo[8];
    #pragma unroll
    for (int i = 0; i < 8; i++)
        split3(J.W[(size_t)(krow + i) * J.N + col], hi[i], mi[i], lo[i]);
    size_t ps = (size_t)J.K * J.N;
    *(uint4*)(J.Wp + (size_t)idx * 8)          = *(uint4*)hi;
    *(uint4*)(J.Wp + ps + (size_t)idx * 8)     = *(uint4*)mi;
    *(uint4*)(J.Wp + 2 * ps + (size_t)idx * 8) = *(uint4*)lo;
}

// fc pack (single bf16, proven)
__global__ __launch_bounds__(256) void pack_w(
    const float* __restrict__ W, ushortT* __restrict__ Wp, int N, int K)
{
    int idx = blockIdx.x * 256 + threadIdx.x;
    int lane = idx & 63;
    int t = idx >> 6;
    int KC = K >> 5;
    int ntile = t / KC, kc = t - ntile * KC;
    int col = ntile * 16 + (lane & 15);
    int krow = kc * 32 + (lane >> 4) * 8;
    ushortT tmp[8];
    #pragma unroll
    for (int i = 0; i < 8; i++)
        tmp[i] = f2bf(W[(size_t)(krow + i) * N + col]);
    *(uint4*)(Wp + (size_t)idx * 8) = *(uint4*)tmp;
}

// ---------------------------------------------------------------------------
// split6 GEMM body (shared by classic kernels and the mega-kernel).
// ---------------------------------------------------------------------------
struct GemmJob {
    const float*   A;
    const float*   W;
    const ushortT* Wp;
    unsigned long long ps;
    int kc_base;
    int KCtot;
    float* Cpart;
    int lda;
};

template<bool PRESPLIT>
__device__ __forceinline__ void gemm6_body(
    const GemmJob& J, int xblk, int ks, int nkc, int N,
    ushortT* Ahi, ushortT* Amid, ushortT* Alo)
{
    const int tid = threadIdx.x;
    const int lane = tid & 63;
    const int wave = tid >> 6;
    const int ntile = xblk * 4 + wave;
    const int col = ntile * 16 + (lane & 15);
    const int kfrag = (lane >> 4) * 8;

    f32x4 acc[4] = {};
    const int arow = (tid >> 6) * 16 + (tid & 15);
    const int kgof = ((tid >> 4) & 3) * 8;

    for (int c = 0; c < nkc; c++) {
        const int kc = ks * nkc + c;
        const float* ar = J.A + (size_t)arow * J.lda + kc * 32 + kgof;
        float av[8];
        *(float4*)(av)     = *(const float4*)(ar);
        *(float4*)(av + 4) = *(const float4*)(ar + 4);
        ushortT thi[8], tmi[8], tlo[8];
        #pragma unroll
        for (int i = 0; i < 8; i++) split3(av[i], thi[i], tmi[i], tlo[i]);
        ((uint4*)Ahi)[tid]  = *(const uint4*)thi;
        ((uint4*)Amid)[tid] = *(const uint4*)tmi;
        ((uint4*)Alo)[tid]  = *(const uint4*)tlo;

        bf16x8 bh, bm, bl;
        if constexpr (PRESPLIT) {
            size_t fi = (((size_t)ntile * J.KCtot + (J.kc_base + kc)) * 64 + lane) * 8;
            bh = *(const bf16x8*)(J.Wp + fi);
            bm = *(const bf16x8*)(J.Wp + J.ps + fi);
            bl = *(const bf16x8*)(J.Wp + 2 * J.ps + fi);
        } else {
            const float* wp = J.W + (size_t)((J.kc_base + kc) * 32 + kfrag) * N + col;
            ushortT whi[8], wmi[8], wlo[8];
            #pragma unroll
            for (int i = 0; i < 8; i++)
                split3(wp[(size_t)i * N], whi[i], wmi[i], wlo[i]);
            bh = *(const bf16x8*)whi;
            bm = *(const bf16x8*)wmi;
            bl = *(const bf16x8*)wlo;
        }

        __syncthreads();
        #pragma unroll
        for (int mi = 0; mi < 4; mi++) {
            bf16x8 ah = *(const bf16x8*)(Ahi  + (mi * 64 + lane) * 8);
            bf16x8 am = *(const bf16x8*)(Amid + (mi * 64 + lane) * 8);
            bf16x8 al = *(const bf16x8*)(Alo  + (mi * 64 + lane) * 8);
            acc[mi] = __builtin_amdgcn_mfma_f32_16x16x32_bf16(ah, bh, acc[mi], 0, 0, 0);
            acc[mi] = __builtin_amdgcn_mfma_f32_16x16x32_bf16(am, bh, acc[mi], 0, 0, 0);
            acc[mi] = __builtin_amdgcn_mfma_f32_16x16x32_bf16(ah, bm, acc[mi], 0, 0, 0);
            acc[mi] = __builtin_amdgcn_mfma_f32_16x16x32_bf16(am, bm, acc[mi], 0, 0, 0);
            acc[mi] = __builtin_amdgcn_mfma_f32_16x16x32_bf16(al, bh, acc[mi], 0, 0, 0);
            acc[mi] = __builtin_amdgcn_mfma_f32_16x16x32_bf16(ah, bl, acc[mi], 0, 0, 0);
        }
        __syncthreads();
    }

    float* cp = J.Cpart + (size_t)ks * 64 * N;
    #pragma unroll
    for (int mi = 0; mi < 4; mi++) {
        #pragma unroll
        for (int r = 0; r < 4; r++) {
            int m = mi * 16 + (lane >> 4) * 4 + r;
            cp[(size_t)m * N + col] = acc[mi][r];
        }
    }
}

// classic kernel wrapper (2-job fusion via blockIdx.z)
template<bool PRESPLIT>
__global__ __launch_bounds__(256) void gemm6_ks2(
    GemmJob j0, GemmJob j1, int N, int nkc)
{
    __shared__ __align__(16) ushortT Ahi[2048];
    __shared__ __align__(16) ushortT Amid[2048];
    __shared__ __align__(16) ushortT Alo[2048];
    const GemmJob J = blockIdx.z ? j1 : j0;
    gemm6_body<PRESPLIT>(J, blockIdx.x, blockIdx.y, nkc, N, Ahi, Amid, Alo);
}

// ---------------------------------------------------------------------------
// [M,1024] @ [1024,1024] split6 GEMM (keys and memV): grid (U/128, M/64).
// ---------------------------------------------------------------------------
template<bool PRESPLIT>
__global__ __launch_bounds__(256) void gemm_keys(
    const float* __restrict__ A, const float* __restrict__ W,
    const ushortT* __restrict__ Wp, float* __restrict__ C)
{
    const int tid = threadIdx.x;
    const int lane = tid & 63;
    const int wave = tid >> 6;
    const int row0 = blockIdx.y * 64;
    const int nt0 = blockIdx.x * 8 + wave * 2;
    const int col0 = nt0 * 16 + (lane & 15);
    const int kfrag = (lane >> 4) * 8;

    __shared__ __align__(16) ushortT Ahi[2048];
    __shared__ __align__(16) ushortT Amid[2048];
    __shared__ __align__(16) ushortT Alo[2048];

    f32x4 acc[2][4] = {};
    const int arow = row0 + (tid >> 6) * 16 + (tid & 15);
    const int kgof = ((tid >> 4) & 3) * 8;
    const size_t ps = (size_t)U * U;

    for (int kc = 0; kc < 32; kc++) {
        const float* ar = A + (size_t)arow * U + kc * 32 + kgof;
        float av[8];
        *(float4*)(av)     = *(const float4*)(ar);
        *(float4*)(av + 4) = *(const float4*)(ar + 4);
        ushortT thi[8], tmi[8], tlo[8];
        #pragma unroll
        for (int i = 0; i < 8; i++) split3(av[i], thi[i], tmi[i], tlo[i]);
        ((uint4*)Ahi)[tid]  = *(const uint4*)thi;
        ((uint4*)Amid)[tid] = *(const uint4*)tmi;
        ((uint4*)Alo)[tid]  = *(const uint4*)tlo;

        bf16x8 bh[2], bm[2], bl[2];
        #pragma unroll
        for (int j = 0; j < 2; j++) {
            if constexpr (PRESPLIT) {
                size_t fi = (((size_t)(nt0 + j) * 32 + kc) * 64 + lane) * 8;
                bh[j] = *(const bf16x8*)(Wp + fi);
                bm[j] = *(const bf16x8*)(Wp + ps + fi);
                bl[j] = *(const bf16x8*)(Wp + 2 * ps + fi);
            } else {
                const float* wp = W + (size_t)(kc * 32 + kfrag) * U + col0 + j * 16;
                ushortT whi[8], wmi[8], wlo[8];
                #pragma unroll
                for (int i = 0; i < 8; i++)
                    split3(wp[(size_t)i * U], whi[i], wmi[i], wlo[i]);
                bh[j] = *(const bf16x8*)whi;
                bm[j] = *(const bf16x8*)wmi;
                bl[j] = *(const bf16x8*)wlo;
            }
        }

        __syncthreads();
        #pragma unroll
        for (int mi = 0; mi < 4; mi++) {
            bf16x8 ah = *(const bf16x8*)(Ahi  + (mi * 64 + lane) * 8);
            bf16x8 am = *(const bf16x8*)(Amid + (mi * 64 + lane) * 8);
            bf16x8 al = *(const bf16x8*)(Alo  + (mi * 64 + lane) * 8);
            #pragma unroll
            for (int j = 0; j < 2; j++) {
                acc[j][mi] = __builtin_amdgcn_mfma_f32_16x16x32_bf16(ah, bh[j], acc[j][mi], 0, 0, 0);
                acc[j][mi] = __builtin_amdgcn_mfma_f32_16x16x32_bf16(am, bh[j], acc[j][mi], 0, 0, 0);
                acc[j][mi] = __builtin_amdgcn_mfma_f32_16x16x32_bf16(ah, bm[j], acc[j][mi], 0, 0, 0);
                acc[j][mi] = __builtin_amdgcn_mfma_f32_16x16x32_bf16(am, bm[j], acc[j][mi], 0, 0, 0);
                acc[j][mi] = __builtin_amdgcn_mfma_f32_16x16x32_bf16(al, bh[j], acc[j][mi], 0, 0, 0);
                acc[j][mi] = __builtin_amdgcn_mfma_f32_16x16x32_bf16(ah, bl[j], acc[j][mi], 0, 0, 0);
            }
        }
        __syncthreads();
    }

    #pragma unroll
    for (int mi = 0; mi < 4; mi++) {
        #pragma unroll
        for (int r = 0; r < 4; r++) {
            int m = row0 + mi * 16 + (lane >> 4) * 4 + r;
            #pragma unroll
            for (int j = 0; j < 2; j++)
                C[(size_t)m * U + col0 + j * 16] = acc[j][mi][r];
        }
    }
}

// ---------------------------------------------------------------------------
// xe[t] = emb[x[:,t]] @ gk[0:256,:]   grid (U3/64, T)
// ---------------------------------------------------------------------------
template<bool PRESPLIT>
__global__ __launch_bounds__(256) void gemm_xe(
    const int* __restrict__ x, const float* __restrict__ emb,
    const float* __restrict__ gk, const ushortT* __restrict__ gkp,
    float* __restrict__ xe)
{
    const int tid = threadIdx.x;
    const int lane = tid & 63;
    const int wave = tid >> 6;
    const int t = blockIdx.y;
    const int ntile = blockIdx.x * 4 + wave;
    const int col = ntile * 16 + (lane & 15);
    const int kfrag = (lane >> 4) * 8;

    __shared__ __align__(16) ushortT Ahi[2048];
    __shared__ __align__(16) ushortT Amid[2048];
    __shared__ __align__(16) ushortT Alo[2048];

    f32x4 acc[4] = {};
    const int b = (tid >> 6) * 16 + (tid & 15);
    const int tok = x[b * T + t];
    const int kgof = ((tid >> 4) & 3) * 8;
    const size_t ps = (size_t)KXM * U3;

    for (int kc = 0; kc < E / 32; kc++) {
        const float* ar = emb + (size_t)tok * E + kc * 32 + kgof;
        float av[8];
        *(float4*)(av)     = *(const float4*)(ar);
        *(float4*)(av + 4) = *(const float4*)(ar + 4);
        ushortT thi[8], tmi[8], tlo[8];
        #pragma unroll
        for (int i = 0; i < 8; i++) split3(av[i], thi[i], tmi[i], tlo[i]);
        ((uint4*)Ahi)[tid]  = *(const uint4*)thi;
        ((uint4*)Amid)[tid] = *(const uint4*)tmi;
        ((uint4*)Alo)[tid]  = *(const uint4*)tlo;

        bf16x8 bh, bm, bl;
        if constexpr (PRESPLIT) {
            size_t fi = (((size_t)ntile * 40 + kc) * 64 + lane) * 8;   // gk KCtot=40
            bh = *(const bf16x8*)(gkp + fi);
            bm = *(const bf16x8*)(gkp + ps + fi);
            bl = *(const bf16x8*)(gkp + 2 * ps + fi);
        } else {
            const float* wp = gk + (size_t)(kc * 32 + kfrag) * U3 + col;
            ushortT whi[8], wmi[8], wlo[8];
            #pragma unroll
            for (int i = 0; i < 8; i++)
                split3(wp[(size_t)i * U3], whi[i], wmi[i], wlo[i]);
            bh = *(const bf16x8*)whi;
            bm = *(const bf16x8*)wmi;
            bl = *(const bf16x8*)wlo;
        }

        __syncthreads();
        #pragma unroll
        for (int mi = 0; mi < 4; mi++) {
            bf16x8 ah = *(const bf16x8*)(Ahi  + (mi * 64 + lane) * 8);
            bf16x8 am = *(const bf16x8*)(Amid + (mi * 64 + lane) * 8);
            bf16x8 al = *(const bf16x8*)(Alo  + (mi * 64 + lane) * 8);
            acc[mi] = __builtin_amdgcn_mfma_f32_16x16x32_bf16(ah, bh, acc[mi], 0, 0, 0);
            acc[mi] = __builtin_amdgcn_mfma_f32_16x16x32_bf16(am, bh, acc[mi], 0, 0, 0);
            acc[mi] = __builtin_amdgcn_mfma_f32_16x16x32_bf16(ah, bm, acc[mi], 0, 0, 0);
            acc[mi] = __builtin_amdgcn_mfma_f32_16x16x32_bf16(am, bm, acc[mi], 0, 0, 0);
            acc[mi] = __builtin_amdgcn_mfma_f32_16x16x32_bf16(al, bh, acc[mi], 0, 0, 0);
            acc[mi] = __builtin_amdgcn_mfma_f32_16x16x32_bf16(ah, bl, acc[mi], 0, 0, 0);
        }
        __syncthreads();
    }

    #pragma unroll
    for (int mi = 0; mi < 4; mi++) {
        #pragma unroll
        for (int r = 0; r < 4; r++) {
            int m = mi * 16 + (lane >> 4) * 4 + r;
            xe[((size_t)t * 64 + m) * U3 + col] = acc[mi][r];
        }
    }
}

// ---------------------------------------------------------------------------
// Batched fc GEMM (R10 M64, measured best): XCD-pinned t-major.
// ---------------------------------------------------------------------------
__global__ __launch_bounds__(256) void gemm_fcB(
    const float* __restrict__ A, const ushortT* __restrict__ Wp,
    const float* __restrict__ bias, float* __restrict__ C)
{
    const int xcd = blockIdx.x & 7;
    const int rem = blockIdx.x >> 3;        // g*19 + t
    const int g = rem / T;
    const int tg = rem - g * T;
    const int strip = g * 8 + xcd;
    if (strip >= V / 128) return;

    const int tid = threadIdx.x;
    const int lane = tid & 63;
    const int wave = tid >> 6;
    const int nt0 = strip * 8 + wave * 2;
    const int col0 = nt0 * 16 + (lane & 15);

    __shared__ __align__(16) ushortT As[2][2048];

    f32x4 acc[2][4] = {};
    const int arow = (tid >> 6) * 16 + (tid & 15);
    const float* At = A + (size_t)tg * 64 * U;
    float* Ct = C + (size_t)tg * V;
    const int kgof = ((tid >> 4) & 3) * 8;

    for (int it = 0; it < 16; it++) {
        #pragma unroll
        for (int c = 0; c < 2; c++) {
            const float* ar = At + (size_t)arow * U + (it * 2 + c) * 32 + kgof;
            float4 f0 = *(const float4*)(ar);
            float4 f1 = *(const float4*)(ar + 4);
            ushortT tmp[8] = { f2bf(f0.x), f2bf(f0.y), f2bf(f0.z), f2bf(f0.w),
                               f2bf(f1.x), f2bf(f1.y), f2bf(f1.z), f2bf(f1.w) };
            ((uint4*)As[c])[tid] = *(const uint4*)tmp;
        }
        bf16x8 b[2][2];
        #pragma unroll
        for (int c = 0; c < 2; c++)
            #pragma unroll
            for (int j = 0; j < 2; j++)
                b[c][j] = *(const bf16x8*)(Wp +
                    (((size_t)(nt0 + j) * 32 + it * 2 + c) * 64 + lane) * 8);
        __syncthreads();
        #pragma unroll
        for (int c = 0; c < 2; c++) {
            #pragma unroll
            for (int mi = 0; mi < 4; mi++) {
                bf16x8 a = *(const bf16x8*)(As[c] + (mi * 64 + lane) * 8);
                #pragma unroll
                for (int j = 0; j < 2; j++)
                    acc[j][mi] = __builtin_amdgcn_mfma_f32_16x16x32_bf16(a, b[c][j], acc[j][mi], 0, 0, 0);
            }
        }
        __syncthreads();
    }

    #pragma unroll
    for (int j = 0; j < 2; j++) {
        const float bv = bias[col0 + j * 16];
        #pragma unroll
        for (int mi = 0; mi < 4; mi++) {
            #pragma unroll
            for (int r = 0; r < 4; r++) {
                int m = mi * 16 + (lane >> 4) * 4 + r;
                __builtin_nontemporal_store(acc[j][mi][r] + bv,
                    &Ct[(size_t)m * (T * V) + col0 + j * 16]);
            }
        }
    }
}

// ---------------------------------------------------------------------------
// gates + scores + softmax body (one block handles batch b).
// ---------------------------------------------------------------------------
__device__ __forceinline__ void gs_body(
    int b, const float* xe_t, const float* xm_part, const float* hm_part,
    const float* gb, const float* keys, float* h, float* pn_out, int use_xm,
    float* hs, float* p)
{
    const int tid = threadIdx.x;

    #pragma unroll
    for (int k = 0; k < 4; k++) {
        int u = k * 256 + tid;
        float xv[3], hv[3];
        #pragma unroll
        for (int g = 0; g < 3; g++) {
            int j = g * U + u;
            float xs = xe_t[(size_t)b * U3 + j] + gb[j];
            float hsum = gb[U3 + j];
            if (use_xm) {
                #pragma unroll
                for (int pp = 0; pp < 8; pp++)
                    xs += xm_part[((size_t)pp * 64 + b) * U3 + j];
            }
            #pragma unroll
            for (int pp = 0; pp < 8; pp++)
                hsum += hm_part[((size_t)pp * 64 + b) * U3 + j];
            xv[g] = xs; hv[g] = hsum;
        }
        float z = 1.f / (1.f + expf(-(xv[0] + hv[0])));
        float r = 1.f / (1.f + expf(-(xv[1] + hv[1])));
        float hh = tanhf(xv[2] + r * hv[2]);
        float hn = z * h[(size_t)b * U + u] + (1.f - z) * hh;
        h[(size_t)b * U + u] = hn;
        hs[u] = hn;
    }
    __syncthreads();

    const int wave = tid >> 6, lane = tid & 63;
    for (int s = wave; s < S; s += 4) {
        const float* kr = keys + ((size_t)b * S + s) * U;
        float acc = 0.f;
        #pragma unroll
        for (int c = 0; c < 4; c++) {
            int off = c * 256 + lane * 4;
            float4 kv = *(const float4*)(kr + off);
            float4 hv4 = *(const float4*)(hs + off);
            acc += kv.x * hv4.x + kv.y * hv4.y + kv.z * hv4.z + kv.w * hv4.w;
        }
        #pragma unroll
        for (int off = 32; off > 0; off >>= 1) acc += __shfl_down(acc, off);
        if (lane == 0) p[s] = acc;
    }
    __syncthreads();

    float m = -1e30f;
    #pragma unroll 8
    for (int s = 0; s < S; s++) m = fmaxf(m, p[s]);
    float sum = 0.f;
    #pragma unroll 8
    for (int s = 0; s < S; s++) sum += expf(p[s] - m);
    if (tid < S) pn_out[b * S + tid] = expf(p[tid] - m) / sum;
}

__global__ __launch_bounds__(256) void gs_fused(
    const float* xe_t, const float* xm_part, const float* hm_part,
    const float* gb, const float* keys, float* h, float* pn_out, int use_xm)
{
    __shared__ __align__(16) float hs[U];
    __shared__ float p[S];
    gs_body(blockIdx.x, xe_t, xm_part, hm_part, gb, keys, h, pn_out, use_xm, hs, p);
}

// ---------------------------------------------------------------------------
// pnmv body: attnv = sum8(ah_part) + pn @ memV for (b, col-quarter uq)
// ---------------------------------------------------------------------------
__device__ __forceinline__ void pnmv_body(
    int b, int uq, const float* ah_part, const float* pn,
    const float* memV, float* dst, float* pl)
{
    const int u = uq * 256 + threadIdx.x;
    if (threadIdx.x < S) pl[threadIdx.x] = pn[b * S + threadIdx.x];
    __syncthreads();
    float acc = 0.f;
    #pragma unroll
    for (int p = 0; p < 8; p++)
        acc += ah_part[((size_t)p * 64 + b) * U + u];
    #pragma unroll 8
    for (int s = 0; s < S; s++)
        acc += pl[s] * memV[((size_t)b * S + s) * U + u];
    dst[(size_t)b * U + u] = acc;
}

__global__ __launch_bounds__(256) void pnmv_kernel(
    const float* ah_part, const float* pn, const float* memV, float* dst)
{
    __shared__ float pl[S];
    pnmv_body(blockIdx.x, blockIdx.y, ah_part, pn, memV, dst, pl);
}

// ---------------------------------------------------------------------------
// Device-wide barrier: monotonic counter, memset to 0 each launch.
// ---------------------------------------------------------------------------
__device__ __forceinline__ void gbar(unsigned* cnt, unsigned& barno)
{
    __syncthreads();
    barno++;
    if (threadIdx.x == 0) {
        __threadfence();                       // release prior writes
        atomicAdd(cnt, 1u);
        const unsigned target = barno * (unsigned)NBLK;
        while (atomicAdd(cnt, 0u) < target)
            __builtin_amdgcn_s_sleep(8);
    }
    __syncthreads();
    __threadfence();                           // acquire
}

// ---------------------------------------------------------------------------
// Persistent mega-kernel: all T steps, 4 device barriers per step.
// Phase math is bit-identical to the classic kernels (shared bodies).
// ---------------------------------------------------------------------------
struct LoopArgs {
    const float* xe; const float* gb; const float* keys; const float* memV;
    float* h; float* pn; float* hm_part; float* xm_part; float* ah_part;
    float* attnv_all;
    const ushortT* gkp; const ushortT* grkp; const ushortT* wtpp;
    unsigned* bar;
};

__global__ __launch_bounds__(256, 3) void loop_mega(LoopArgs a)
{
    __shared__ __align__(16) unsigned char smem[12288];
    ushortT* Ahi  = (ushortT*)smem;
    ushortT* Amid = Ahi + 2048;
    ushortT* Alo  = Amid + 2048;
    float* fsh = (float*)smem;                 // phase B: hs[1024], p[80]

    const int bid = blockIdx.x;
    unsigned barno = 0;

    for (int t = 0; t < T; t++) {
        // Phase A: hm (z=0, 384 blocks) / xm (z=1, 384 blocks, t>0)
        {
            int z = bid / 384;
            int rem = bid - z * 384;
            int xb = rem % 48;
            int ks = rem / 48;
            if (z == 0) {
                GemmJob job = { a.h, nullptr, a.grkp, (size_t)U * U3, 0, 32,
                                a.hm_part, U };
                gemm6_body<true>(job, xb, ks, 4, U3, Ahi, Amid, Alo);
            } else if (t > 0) {
                GemmJob job = { a.attnv_all + (size_t)(t - 1) * B * U, nullptr,
                                a.gkp, (size_t)KXM * U3, 8, 40, a.xm_part, U };
                gemm6_body<true>(job, xb, ks, 4, U3, Ahi, Amid, Alo);
            }
        }
        gbar(a.bar, barno);

        // Phase B: gates + scores + softmax (64 blocks)
        if (bid < B) {
            gs_body(bid, a.xe + (size_t)t * B * U3, a.xm_part, a.hm_part,
                    a.gb, a.keys, a.h, a.pn, t > 0 ? 1 : 0, fsh, fsh + U);
        }
        gbar(a.bar, barno);

        // Phase C: ah = h @ Wtop (128 blocks: 16 x-tiles x 8 ks)
        if (bid < 128) {
            int xb = bid & 15;
            int ks = bid >> 4;
            GemmJob job = { a.h, nullptr, a.wtpp, (size_t)U * U, 0, 32,
                            a.ah_part, U };
            gemm6_body<true>(job, xb, ks, 4, U, Ahi, Amid, Alo);
        }
        gbar(a.bar, barno);

        // Phase D: attnv_all[t] = sum8(ah) + pn @ memV (256 blocks)
        if (bid < 256) {
            pnmv_body(bid & 63, bid >> 6, a.ah_part, a.pn, a.memV,
                      a.attnv_all + (size_t)t * B * U, fsh);
        }
        gbar(a.bar, barno);
    }
}

// ---------------------------------------------------------------------------
extern "C" void kernel_launch(void* const* d_in, const int* in_sizes, int n_in,
                              void* d_out, int out_size, void* d_ws, size_t ws_size,
                              hipStream_t stream)
{
    const int*   x      = (const int*)  d_in[0];
    const float* enc    = (const float*)d_in[1];
    const float* memory = (const float*)d_in[2];
    const float* emb    = (const float*)d_in[3];
    const float* gk     = (const float*)d_in[4];
    const float* grk    = (const float*)d_in[5];
    const float* gb     = (const float*)d_in[6];
    const float* memW   = (const float*)d_in[7];
    const float* attnW  = (const float*)d_in[8];
    const float* fcW    = (const float*)d_in[9];
    const float* fcb    = (const float*)d_in[10];
    float* out = (float*)d_out;

    const float* Wtop = attnW;
    const float* Wbot = attnW + (size_t)U * U;

    char* p = (char*)d_ws;
    auto alloc = [&](size_t bytes) { char* r = p; p += (bytes + 255) & ~(size_t)255; return r; };
    ushortT* fcWp      = (ushortT*)alloc((size_t)U * V * 2);
    float*   keys      = (float*)  alloc((size_t)B * S * U * 4);
    float*   memV      = (float*)  alloc((size_t)B * S * U * 4);
    float*   xe        = (float*)  alloc((size_t)T * B * U3 * 4);
    float*   xm_part   = (float*)  alloc((size_t)8 * B * U3 * 4);
    float*   hm_part   = (float*)  alloc((size_t)8 * B * U3 * 4);
    float*   ah_part   = (float*)  alloc((size_t)8 * B * U * 4);
    float*   h         = (float*)  alloc((size_t)B * U * 4);
    float*   attnv_all = (float*)  alloc((size_t)T * B * U * 4);
    float*   pn        = (float*)  alloc((size_t)B * S * 4);
    unsigned* bar      = (unsigned*)alloc(256);
    ushortT* gkp       = (ushortT*)alloc((size_t)KXM * U3 * 2 * 3);
    ushortT* grkp      = (ushortT*)alloc((size_t)U * U3 * 2 * 3);
    ushortT* wtpp      = (ushortT*)alloc((size_t)U * U * 2 * 3);
    ushortT* wbpp      = (ushortT*)alloc((size_t)U * U * 2 * 3);
    ushortT* mwp       = (ushortT*)alloc((size_t)U * U * 2 * 3);
    const bool PS = (size_t)(p - (char*)d_ws) <= ws_size;

    dim3 blk(256);

    (void)hipMemsetAsync(bar, 0, 256, stream);
    if (PS) {
        PackJob j0 = { gk,   gkp,  U3, KXM, 0 };
        PackJob j1 = { grk,  grkp, U3, U,   1920 };
        PackJob j2 = { Wtop, wtpp, U,  U,   1920 + 1536 };
        PackJob j3 = { Wbot, wbpp, U,  U,   1920 + 1536 + 512 };
        PackJob j4 = { memW, mwp,  U,  U,   1920 + 1536 + 512 + 512 };
        pack_w3_all<<<1920 + 1536 + 512 + 512 + 512, blk, 0, stream>>>(j0, j1, j2, j3, j4);
    }
    pack_w<<<(size_t)U * V / 8 / 256, blk, 0, stream>>>(fcW, fcWp, V, U);
    (void)hipMemcpyAsync(h, enc, (size_t)B * U * sizeof(float),
                         hipMemcpyDeviceToDevice, stream);

    if (PS) gemm_xe<true><<<dim3(U3 / 64, T), blk, 0, stream>>>(x, emb, gk, gkp, xe);
    else    gemm_xe<false><<<dim3(U3 / 64, T), blk, 0, stream>>>(x, emb, gk, gkp, xe);

    if (PS) gemm_keys<true><<<dim3(U / 128, B * S / 64), blk, 0, stream>>>(memory, memW, mwp, keys);
    else    gemm_keys<false><<<dim3(U / 128, B * S / 64), blk, 0, stream>>>(memory, memW, mwp, keys);

    if (PS) gemm_keys<true><<<dim3(U / 128, B * S / 64), blk, 0, stream>>>(memory, Wbot, wbpp, memV);
    else    gemm_keys<false><<<dim3(U / 128, B * S / 64), blk, 0, stream>>>(memory, Wbot, wbpp, memV);

    if (PS) {
        // persistent mega-kernel: the whole T-loop in one launch
        LoopArgs la = { xe, gb, keys, memV, h, pn, hm_part, xm_part, ah_part,
                        attnv_all, gkp, grkp, wtpp, bar };
        loop_mega<<<NBLK, blk, 0, stream>>>(la);
    } else {
        // classic 4-kernel loop (R16-proven)
        GemmJob job_hm = { h, grk, grkp, (size_t)U * U3, 0, 32, hm_part, U };
        GemmJob job_ah = { h, Wtop, wtpp, (size_t)U * U, 0, 32, ah_part, U };
        for (int t = 0; t < T; t++) {
            GemmJob job_xm = { attnv_all + (size_t)(t - 1) * B * U, gk, gkp,
                               (size_t)KXM * U3, 8, 40, xm_part, U };
            dim3 g1(U3 / 64, 8, t > 0 ? 2 : 1);
            gemm6_ks2<false><<<g1, blk, 0, stream>>>(job_hm, job_xm, U3, 4);
            gs_fused<<<B, blk, 0, stream>>>(
                xe + (size_t)t * B * U3, xm_part, hm_part, gb, keys, h, pn,
                t > 0 ? 1 : 0);
            dim3 g2(U / 64, 8, 1);
            gemm6_ks2<false><<<g2, blk, 0, stream>>>(job_ah, job_ah, U, 4);
            pnmv_kernel<<<dim3(B, U / 256), blk, 0, stream>>>(
                ah_part, pn, memV, attnv_all + (size_t)t * B * U);
        }
    }

    // all logits at once: [T*64, U] @ [U, V] + fcb (M64, XCD-pinned)
    gemm_fcB<<<32 * T * 8, blk, 0, stream>>>(attnv_all, fcWp, fcb, out);
}

// Round 19
// 1121.627 us; speedup vs baseline: 9.8197x; 9.8197x over previous
//
#include <hip/hip_runtime.h>
#include <hip/hip_bf16.h>
#include <math.h>

#define B 64
#define T 19
#define S 80
#define V 32000
#define E 256
#define U 1024
#define U3 (3*U)        // 3072
#define KXM (E+U)       // 1280

typedef unsigned short ushortT;
typedef __attribute__((ext_vector_type(8))) __bf16 bf16x8;
typedef __attribute__((ext_vector_type(4))) float f32x4;

__device__ __forceinline__ ushortT f2bf(float f) {
    unsigned int u = __float_as_uint(f);
    u = (u + 0x7FFF + ((u >> 16) & 1)) >> 16;   // RNE
    return (ushortT)u;
}
__device__ __forceinline__ float bf2f(ushortT u) {
    return __uint_as_float(((unsigned int)u) << 16);
}
__device__ __forceinline__ void split3(float v, ushortT& hi, ushortT& mid, ushortT& lo) {
    hi = f2bf(v);
    float r1 = v - bf2f(hi);
    mid = f2bf(r1);
    float r2 = r1 - bf2f(mid);
    lo = f2bf(r2);
}

// ---------------------------------------------------------------------------
// Merged pre-split weight pack: 5 matrices in one launch.
// ---------------------------------------------------------------------------
struct PackJob { const float* W; ushortT* Wp; int N; int K; int blk0; };

__global__ __launch_bounds__(256) void pack_w3_all(
    PackJob j0, PackJob j1, PackJob j2, PackJob j3, PackJob j4)
{
    int bid = blockIdx.x;
    PackJob J = j4;
    if (bid < j1.blk0) J = j0;
    else if (bid < j2.blk0) J = j1;
    else if (bid < j3.blk0) J = j2;
    else if (bid < j4.blk0) J = j3;

    int idx = (bid - J.blk0) * 256 + threadIdx.x;
    int lane = idx & 63;
    int t = idx >> 6;
    int KC = J.K >> 5;
    int ntile = t / KC, kc = t - ntile * KC;
    int col = ntile * 16 + (lane & 15);
    int krow = kc * 32 + (lane >> 4) * 8;
    ushortT hi[8], mi[8], lo[8];
    #pragma unroll
    for (int i = 0; i < 8; i++)
        split3(J.W[(size_t)(krow + i) * J.N + col], hi[i], mi[i], lo[i]);
    size_t ps = (size_t)J.K * J.N;
    *(uint4*)(J.Wp + (size_t)idx * 8)          = *(uint4*)hi;
    *(uint4*)(J.Wp + ps + (size_t)idx * 8)     = *(uint4*)mi;
    *(uint4*)(J.Wp + 2 * ps + (size_t)idx * 8) = *(uint4*)lo;
}

// fc pack (single bf16, proven)
__global__ __launch_bounds__(256) void pack_w(
    const float* __restrict__ W, ushortT* __restrict__ Wp, int N, int K)
{
    int idx = blockIdx.x * 256 + threadIdx.x;
    int lane = idx & 63;
    int t = idx >> 6;
    int KC = K >> 5;
    int ntile = t / KC, kc = t - ntile * KC;
    int col = ntile * 16 + (lane & 15);
    int krow = kc * 32 + (lane >> 4) * 8;
    ushortT tmp[8];
    #pragma unroll
    for (int i = 0; i < 8; i++)
        tmp[i] = f2bf(W[(size_t)(krow + i) * N + col]);
    *(uint4*)(Wp + (size_t)idx * 8) = *(uint4*)tmp;
}

// ---------------------------------------------------------------------------
// split6 GEMM body (shared).
// ---------------------------------------------------------------------------
struct GemmJob {
    const float*   A;
    const float*   W;
    const ushortT* Wp;
    unsigned long long ps;
    int kc_base;
    int KCtot;
    float* Cpart;
    int lda;
};

template<bool PRESPLIT>
__device__ __forceinline__ void gemm6_body(
    const GemmJob& J, int xblk, int ks, int nkc, int N,
    ushortT* Ahi, ushortT* Amid, ushortT* Alo)
{
    const int tid = threadIdx.x;
    const int lane = tid & 63;
    const int wave = tid >> 6;
    const int ntile = xblk * 4 + wave;
    const int col = ntile * 16 + (lane & 15);
    const int kfrag = (lane >> 4) * 8;

    f32x4 acc[4] = {};
    const int arow = (tid >> 6) * 16 + (tid & 15);
    const int kgof = ((tid >> 4) & 3) * 8;

    for (int c = 0; c < nkc; c++) {
        const int kc = ks * nkc + c;
        const float* ar = J.A + (size_t)arow * J.lda + kc * 32 + kgof;
        float av[8];
        *(float4*)(av)     = *(const float4*)(ar);
        *(float4*)(av + 4) = *(const float4*)(ar + 4);
        ushortT thi[8], tmi[8], tlo[8];
        #pragma unroll
        for (int i = 0; i < 8; i++) split3(av[i], thi[i], tmi[i], tlo[i]);
        ((uint4*)Ahi)[tid]  = *(const uint4*)thi;
        ((uint4*)Amid)[tid] = *(const uint4*)tmi;
        ((uint4*)Alo)[tid]  = *(const uint4*)tlo;

        bf16x8 bh, bm, bl;
        if constexpr (PRESPLIT) {
            size_t fi = (((size_t)ntile * J.KCtot + (J.kc_base + kc)) * 64 + lane) * 8;
            bh = *(const bf16x8*)(J.Wp + fi);
            bm = *(const bf16x8*)(J.Wp + J.ps + fi);
            bl = *(const bf16x8*)(J.Wp + 2 * J.ps + fi);
        } else {
            const float* wp = J.W + (size_t)((J.kc_base + kc) * 32 + kfrag) * N + col;
            ushortT whi[8], wmi[8], wlo[8];
            #pragma unroll
            for (int i = 0; i < 8; i++)
                split3(wp[(size_t)i * N], whi[i], wmi[i], wlo[i]);
            bh = *(const bf16x8*)whi;
            bm = *(const bf16x8*)wmi;
            bl = *(const bf16x8*)wlo;
        }

        __syncthreads();
        #pragma unroll
        for (int mi = 0; mi < 4; mi++) {
            bf16x8 ah = *(const bf16x8*)(Ahi  + (mi * 64 + lane) * 8);
            bf16x8 am = *(const bf16x8*)(Amid + (mi * 64 + lane) * 8);
            bf16x8 al = *(const bf16x8*)(Alo  + (mi * 64 + lane) * 8);
            acc[mi] = __builtin_amdgcn_mfma_f32_16x16x32_bf16(ah, bh, acc[mi], 0, 0, 0);
            acc[mi] = __builtin_amdgcn_mfma_f32_16x16x32_bf16(am, bh, acc[mi], 0, 0, 0);
            acc[mi] = __builtin_amdgcn_mfma_f32_16x16x32_bf16(ah, bm, acc[mi], 0, 0, 0);
            acc[mi] = __builtin_amdgcn_mfma_f32_16x16x32_bf16(am, bm, acc[mi], 0, 0, 0);
            acc[mi] = __builtin_amdgcn_mfma_f32_16x16x32_bf16(al, bh, acc[mi], 0, 0, 0);
            acc[mi] = __builtin_amdgcn_mfma_f32_16x16x32_bf16(ah, bl, acc[mi], 0, 0, 0);
        }
        __syncthreads();
    }

    float* cp = J.Cpart + (size_t)ks * 64 * N;
    #pragma unroll
    for (int mi = 0; mi < 4; mi++) {
        #pragma unroll
        for (int r = 0; r < 4; r++) {
            int m = mi * 16 + (lane >> 4) * 4 + r;
            cp[(size_t)m * N + col] = acc[mi][r];
        }
    }
}

// classic kernel wrapper (2-job fusion via blockIdx.z)
template<bool PRESPLIT>
__global__ __launch_bounds__(256) void gemm6_ks2(
    GemmJob j0, GemmJob j1, int N, int nkc)
{
    __shared__ __align__(16) ushortT Ahi[2048];
    __shared__ __align__(16) ushortT Amid[2048];
    __shared__ __align__(16) ushortT Alo[2048];
    const GemmJob J = blockIdx.z ? j1 : j0;
    gemm6_body<PRESPLIT>(J, blockIdx.x, blockIdx.y, nkc, N, Ahi, Amid, Alo);
}

// ---------------------------------------------------------------------------
// [M,1024] @ [1024,1024] split6 GEMM (keys and memV): grid (U/128, M/64).
// ---------------------------------------------------------------------------
template<bool PRESPLIT>
__global__ __launch_bounds__(256) void gemm_keys(
    const float* __restrict__ A, const float* __restrict__ W,
    const ushortT* __restrict__ Wp, float* __restrict__ C)
{
    const int tid = threadIdx.x;
    const int lane = tid & 63;
    const int wave = tid >> 6;
    const int row0 = blockIdx.y * 64;
    const int nt0 = blockIdx.x * 8 + wave * 2;
    const int col0 = nt0 * 16 + (lane & 15);
    const int kfrag = (lane >> 4) * 8;

    __shared__ __align__(16) ushortT Ahi[2048];
    __shared__ __align__(16) ushortT Amid[2048];
    __shared__ __align__(16) ushortT Alo[2048];

    f32x4 acc[2][4] = {};
    const int arow = row0 + (tid >> 6) * 16 + (tid & 15);
    const int kgof = ((tid >> 4) & 3) * 8;
    const size_t ps = (size_t)U * U;

    for (int kc = 0; kc < 32; kc++) {
        const float* ar = A + (size_t)arow * U + kc * 32 + kgof;
        float av[8];
        *(float4*)(av)     = *(const float4*)(ar);
        *(float4*)(av + 4) = *(const float4*)(ar + 4);
        ushortT thi[8], tmi[8], tlo[8];
        #pragma unroll
        for (int i = 0; i < 8; i++) split3(av[i], thi[i], tmi[i], tlo[i]);
        ((uint4*)Ahi)[tid]  = *(const uint4*)thi;
        ((uint4*)Amid)[tid] = *(const uint4*)tmi;
        ((uint4*)Alo)[tid]  = *(const uint4*)tlo;

        bf16x8 bh[2], bm[2], bl[2];
        #pragma unroll
        for (int j = 0; j < 2; j++) {
            if constexpr (PRESPLIT) {
                size_t fi = (((size_t)(nt0 + j) * 32 + kc) * 64 + lane) * 8;
                bh[j] = *(const bf16x8*)(Wp + fi);
                bm[j] = *(const bf16x8*)(Wp + ps + fi);
                bl[j] = *(const bf16x8*)(Wp + 2 * ps + fi);
            } else {
                const float* wp = W + (size_t)(kc * 32 + kfrag) * U + col0 + j * 16;
                ushortT whi[8], wmi[8], wlo[8];
                #pragma unroll
                for (int i = 0; i < 8; i++)
                    split3(wp[(size_t)i * U], whi[i], wmi[i], wlo[i]);
                bh[j] = *(const bf16x8*)whi;
                bm[j] = *(const bf16x8*)wmi;
                bl[j] = *(const bf16x8*)wlo;
            }
        }

        __syncthreads();
        #pragma unroll
        for (int mi = 0; mi < 4; mi++) {
            bf16x8 ah = *(const bf16x8*)(Ahi  + (mi * 64 + lane) * 8);
            bf16x8 am = *(const bf16x8*)(Amid + (mi * 64 + lane) * 8);
            bf16x8 al = *(const bf16x8*)(Alo  + (mi * 64 + lane) * 8);
            #pragma unroll
            for (int j = 0; j < 2; j++) {
                acc[j][mi] = __builtin_amdgcn_mfma_f32_16x16x32_bf16(ah, bh[j], acc[j][mi], 0, 0, 0);
                acc[j][mi] = __builtin_amdgcn_mfma_f32_16x16x32_bf16(am, bh[j], acc[j][mi], 0, 0, 0);
                acc[j][mi] = __builtin_amdgcn_mfma_f32_16x16x32_bf16(ah, bm[j], acc[j][mi], 0, 0, 0);
                acc[j][mi] = __builtin_amdgcn_mfma_f32_16x16x32_bf16(am, bm[j], acc[j][mi], 0, 0, 0);
                acc[j][mi] = __builtin_amdgcn_mfma_f32_16x16x32_bf16(al, bh[j], acc[j][mi], 0, 0, 0);
                acc[j][mi] = __builtin_amdgcn_mfma_f32_16x16x32_bf16(ah, bl[j], acc[j][mi], 0, 0, 0);
            }
        }
        __syncthreads();
    }

    #pragma unroll
    for (int mi = 0; mi < 4; mi++) {
        #pragma unroll
        for (int r = 0; r < 4; r++) {
            int m = row0 + mi * 16 + (lane >> 4) * 4 + r;
            #pragma unroll
            for (int j = 0; j < 2; j++)
                C[(size_t)m * U + col0 + j * 16] = acc[j][mi][r];
        }
    }
}

// ---------------------------------------------------------------------------
// xe[t] = emb[x[:,t]] @ gk[0:256,:]   grid (U3/64, T)
// ---------------------------------------------------------------------------
template<bool PRESPLIT>
__global__ __launch_bounds__(256) void gemm_xe(
    const int* __restrict__ x, const float* __restrict__ emb,
    const float* __restrict__ gk, const ushortT* __restrict__ gkp,
    float* __restrict__ xe)
{
    const int tid = threadIdx.x;
    const int lane = tid & 63;
    const int wave = tid >> 6;
    const int t = blockIdx.y;
    const int ntile = blockIdx.x * 4 + wave;
    const int col = ntile * 16 + (lane & 15);
    const int kfrag = (lane >> 4) * 8;

    __shared__ __align__(16) ushortT Ahi[2048];
    __shared__ __align__(16) ushortT Amid[2048];
    __shared__ __align__(16) ushortT Alo[2048];

    f32x4 acc[4] = {};
    const int b = (tid >> 6) * 16 + (tid & 15);
    const int tok = x[b * T + t];
    const int kgof = ((tid >> 4) & 3) * 8;
    const size_t ps = (size_t)KXM * U3;

    for (int kc = 0; kc < E / 32; kc++) {
        const float* ar = emb + (size_t)tok * E + kc * 32 + kgof;
        float av[8];
        *(float4*)(av)     = *(const float4*)(ar);
        *(float4*)(av + 4) = *(const float4*)(ar + 4);
        ushortT thi[8], tmi[8], tlo[8];
        #pragma unroll
        for (int i = 0; i < 8; i++) split3(av[i], thi[i], tmi[i], tlo[i]);
        ((uint4*)Ahi)[tid]  = *(const uint4*)thi;
        ((uint4*)Amid)[tid] = *(const uint4*)tmi;
        ((uint4*)Alo)[tid]  = *(const uint4*)tlo;

        bf16x8 bh, bm, bl;
        if constexpr (PRESPLIT) {
            size_t fi = (((size_t)ntile * 40 + kc) * 64 + lane) * 8;   // gk KCtot=40
            bh = *(const bf16x8*)(gkp + fi);
            bm = *(const bf16x8*)(gkp + ps + fi);
            bl = *(const bf16x8*)(gkp + 2 * ps + fi);
        } else {
            const float* wp = gk + (size_t)(kc * 32 + kfrag) * U3 + col;
            ushortT whi[8], wmi[8], wlo[8];
            #pragma unroll
            for (int i = 0; i < 8; i++)
                split3(wp[(size_t)i * U3], whi[i], wmi[i], wlo[i]);
            bh = *(const bf16x8*)whi;
            bm = *(const bf16x8*)wmi;
            bl = *(const bf16x8*)wlo;
        }

        __syncthreads();
        #pragma unroll
        for (int mi = 0; mi < 4; mi++) {
            bf16x8 ah = *(const bf16x8*)(Ahi  + (mi * 64 + lane) * 8);
            bf16x8 am = *(const bf16x8*)(Amid + (mi * 64 + lane) * 8);
            bf16x8 al = *(const bf16x8*)(Alo  + (mi * 64 + lane) * 8);
            acc[mi] = __builtin_amdgcn_mfma_f32_16x16x32_bf16(ah, bh, acc[mi], 0, 0, 0);
            acc[mi] = __builtin_amdgcn_mfma_f32_16x16x32_bf16(am, bh, acc[mi], 0, 0, 0);
            acc[mi] = __builtin_amdgcn_mfma_f32_16x16x32_bf16(ah, bm, acc[mi], 0, 0, 0);
            acc[mi] = __builtin_amdgcn_mfma_f32_16x16x32_bf16(am, bm, acc[mi], 0, 0, 0);
            acc[mi] = __builtin_amdgcn_mfma_f32_16x16x32_bf16(al, bh, acc[mi], 0, 0, 0);
            acc[mi] = __builtin_amdgcn_mfma_f32_16x16x32_bf16(ah, bl, acc[mi], 0, 0, 0);
        }
        __syncthreads();
    }

    #pragma unroll
    for (int mi = 0; mi < 4; mi++) {
        #pragma unroll
        for (int r = 0; r < 4; r++) {
            int m = mi * 16 + (lane >> 4) * 4 + r;
            xe[((size_t)t * 64 + m) * U3 + col] = acc[mi][r];
        }
    }
}

// ---------------------------------------------------------------------------
// Batched fc GEMM (R10 M64, measured best): XCD-pinned t-major.
// ---------------------------------------------------------------------------
__global__ __launch_bounds__(256) void gemm_fcB(
    const float* __restrict__ A, const ushortT* __restrict__ Wp,
    const float* __restrict__ bias, float* __restrict__ C)
{
    const int xcd = blockIdx.x & 7;
    const int rem = blockIdx.x >> 3;        // g*19 + t
    const int g = rem / T;
    const int tg = rem - g * T;
    const int strip = g * 8 + xcd;
    if (strip >= V / 128) return;

    const int tid = threadIdx.x;
    const int lane = tid & 63;
    const int wave = tid >> 6;
    const int nt0 = strip * 8 + wave * 2;
    const int col0 = nt0 * 16 + (lane & 15);

    __shared__ __align__(16) ushortT As[2][2048];

    f32x4 acc[2][4] = {};
    const int arow = (tid >> 6) * 16 + (tid & 15);
    const float* At = A + (size_t)tg * 64 * U;
    float* Ct = C + (size_t)tg * V;
    const int kgof = ((tid >> 4) & 3) * 8;

    for (int it = 0; it < 16; it++) {
        #pragma unroll
        for (int c = 0; c < 2; c++) {
            const float* ar = At + (size_t)arow * U + (it * 2 + c) * 32 + kgof;
            float4 f0 = *(const float4*)(ar);
            float4 f1 = *(const float4*)(ar + 4);
            ushortT tmp[8] = { f2bf(f0.x), f2bf(f0.y), f2bf(f0.z), f2bf(f0.w),
                               f2bf(f1.x), f2bf(f1.y), f2bf(f1.z), f2bf(f1.w) };
            ((uint4*)As[c])[tid] = *(const uint4*)tmp;
        }
        bf16x8 b[2][2];
        #pragma unroll
        for (int c = 0; c < 2; c++)
            #pragma unroll
            for (int j = 0; j < 2; j++)
                b[c][j] = *(const bf16x8*)(Wp +
                    (((size_t)(nt0 + j) * 32 + it * 2 + c) * 64 + lane) * 8);
        __syncthreads();
        #pragma unroll
        for (int c = 0; c < 2; c++) {
            #pragma unroll
            for (int mi = 0; mi < 4; mi++) {
                bf16x8 a = *(const bf16x8*)(As[c] + (mi * 64 + lane) * 8);
                #pragma unroll
                for (int j = 0; j < 2; j++)
                    acc[j][mi] = __builtin_amdgcn_mfma_f32_16x16x32_bf16(a, b[c][j], acc[j][mi], 0, 0, 0);
            }
        }
        __syncthreads();
    }

    #pragma unroll
    for (int j = 0; j < 2; j++) {
        const float bv = bias[col0 + j * 16];
        #pragma unroll
        for (int mi = 0; mi < 4; mi++) {
            #pragma unroll
            for (int r = 0; r < 4; r++) {
                int m = mi * 16 + (lane >> 4) * 4 + r;
                __builtin_nontemporal_store(acc[j][mi][r] + bv,
                    &Ct[(size_t)m * (T * V) + col0 + j * 16]);
            }
        }
    }
}

// ---------------------------------------------------------------------------
// GRU gates at full parallelism: grid B*U/256 = 256 blocks.
// Formula/order identical to gs_fused's gates phase (8 partials).
// ---------------------------------------------------------------------------
__global__ __launch_bounds__(256) void gates_k(
    const float* __restrict__ xe_t, const float* __restrict__ xm_part,
    const float* __restrict__ hm_part, const float* __restrict__ gb,
    float* __restrict__ h, int use_xm)
{
    int idx = blockIdx.x * 256 + threadIdx.x;   // B*U
    int b = idx >> 10, u = idx & (U - 1);
    float xv[3], hv[3];
    #pragma unroll
    for (int g = 0; g < 3; g++) {
        int j = g * U + u;
        float xs = xe_t[(size_t)b * U3 + j] + gb[j];
        float hsum = gb[U3 + j];
        if (use_xm) {
            #pragma unroll
            for (int p = 0; p < 8; p++)
                xs += xm_part[((size_t)p * 64 + b) * U3 + j];
        }
        #pragma unroll
        for (int p = 0; p < 8; p++)
            hsum += hm_part[((size_t)p * 64 + b) * U3 + j];
        xv[g] = xs; hv[g] = hsum;
    }
    float z = 1.f / (1.f + expf(-(xv[0] + hv[0])));
    float r = 1.f / (1.f + expf(-(xv[1] + hv[1])));
    float hh = tanhf(xv[2] + r * hv[2]);
    h[idx] = z * h[idx] + (1.f - z) * hh;
}

// ---------------------------------------------------------------------------
// Co-launched scores (1280 blocks, wave per (b,s)) + ah = h@Wtop (128 blocks).
// Both depend only on h. Scores math identical to R5/R14 scores_kernel.
// ---------------------------------------------------------------------------
template<bool PRESPLIT>
__global__ __launch_bounds__(256) void sc_ah(
    const float* __restrict__ h, const float* __restrict__ keys,
    float* __restrict__ scores,
    const float* __restrict__ Wtop, const ushortT* __restrict__ wtpp,
    float* __restrict__ ah_part)
{
    __shared__ __align__(16) ushortT Ahi[2048];
    __shared__ __align__(16) ushortT Amid[2048];
    __shared__ __align__(16) ushortT Alo[2048];

    const int bid = blockIdx.x;
    if (bid < B * S / 4) {
        int gw = bid * 4 + (threadIdx.x >> 6);
        int lane = threadIdx.x & 63;
        int b = gw / S, s = gw - b * S;
        const float* kr = keys + ((size_t)b * S + s) * U;
        const float* hr = h + (size_t)b * U;
        float acc = 0.f;
        #pragma unroll
        for (int c = 0; c < 4; c++) {
            int off = c * 256 + lane * 4;
            float4 kv = *(const float4*)(kr + off);
            float4 hv = *(const float4*)(hr + off);
            acc += kv.x * hv.x + kv.y * hv.y + kv.z * hv.z + kv.w * hv.w;
        }
        #pragma unroll
        for (int off = 32; off > 0; off >>= 1) acc += __shfl_down(acc, off);
        if (lane == 0) scores[gw] = acc;
    } else {
        int r = bid - B * S / 4;       // 0..127: 16 x-tiles x 8 ks
        GemmJob job = { h, Wtop, wtpp, (size_t)U * U, 0, 32, ah_part, U };
        gemm6_body<PRESPLIT>(job, r & 15, r >> 4, 4, U, Ahi, Amid, Alo);
    }
}

// ---------------------------------------------------------------------------
// pnmv + inline softmax: attnv = sum8(ah_part) + softmax(scores)@memV.
// Softmax formulas identical to R14 ctxcat2. grid (B, U/256).
// ---------------------------------------------------------------------------
__global__ __launch_bounds__(256) void pnmv_sm(
    const float* __restrict__ ah_part, const float* __restrict__ scores,
    const float* __restrict__ memV, float* __restrict__ dst)
{
    const int b = blockIdx.x;
    const int u = blockIdx.y * 256 + threadIdx.x;
    __shared__ float p[S];
    __shared__ float pl[S];
    if (threadIdx.x < S) p[threadIdx.x] = scores[b * S + threadIdx.x];
    __syncthreads();
    float m = -1e30f;
    #pragma unroll 8
    for (int s = 0; s < S; s++) m = fmaxf(m, p[s]);
    float sum = 0.f;
    #pragma unroll 8
    for (int s = 0; s < S; s++) sum += expf(p[s] - m);
    if (threadIdx.x < S) pl[threadIdx.x] = expf(p[threadIdx.x] - m) / sum;
    __syncthreads();
    float acc = 0.f;
    #pragma unroll
    for (int pp = 0; pp < 8; pp++)
        acc += ah_part[((size_t)pp * 64 + b) * U + u];
    #pragma unroll 8
    for (int s = 0; s < S; s++)
        acc += pl[s] * memV[((size_t)b * S + s) * U + u];
    dst[(size_t)b * U + u] = acc;
}

// ---------------------------------------------------------------------------
extern "C" void kernel_launch(void* const* d_in, const int* in_sizes, int n_in,
                              void* d_out, int out_size, void* d_ws, size_t ws_size,
                              hipStream_t stream)
{
    const int*   x      = (const int*)  d_in[0];
    const float* enc    = (const float*)d_in[1];
    const float* memory = (const float*)d_in[2];
    const float* emb    = (const float*)d_in[3];
    const float* gk     = (const float*)d_in[4];
    const float* grk    = (const float*)d_in[5];
    const float* gb     = (const float*)d_in[6];
    const float* memW   = (const float*)d_in[7];
    const float* attnW  = (const float*)d_in[8];
    const float* fcW    = (const float*)d_in[9];
    const float* fcb    = (const float*)d_in[10];
    float* out = (float*)d_out;

    const float* Wtop = attnW;
    const float* Wbot = attnW + (size_t)U * U;

    char* p = (char*)d_ws;
    auto alloc = [&](size_t bytes) { char* r = p; p += (bytes + 255) & ~(size_t)255; return r; };
    ushortT* fcWp      = (ushortT*)alloc((size_t)U * V * 2);
    float*   keys      = (float*)  alloc((size_t)B * S * U * 4);
    float*   memV      = (float*)  alloc((size_t)B * S * U * 4);
    float*   xe        = (float*)  alloc((size_t)T * B * U3 * 4);
    float*   xm_part   = (float*)  alloc((size_t)8 * B * U3 * 4);
    float*   hm_part   = (float*)  alloc((size_t)8 * B * U3 * 4);
    float*   ah_part   = (float*)  alloc((size_t)8 * B * U * 4);
    float*   h         = (float*)  alloc((size_t)B * U * 4);
    float*   attnv_all = (float*)  alloc((size_t)T * B * U * 4);
    float*   scores    = (float*)  alloc((size_t)B * S * 4);
    ushortT* gkp       = (ushortT*)alloc((size_t)KXM * U3 * 2 * 3);
    ushortT* grkp      = (ushortT*)alloc((size_t)U * U3 * 2 * 3);
    ushortT* wtpp      = (ushortT*)alloc((size_t)U * U * 2 * 3);
    ushortT* wbpp      = (ushortT*)alloc((size_t)U * U * 2 * 3);
    ushortT* mwp       = (ushortT*)alloc((size_t)U * U * 2 * 3);
    const bool PS = (size_t)(p - (char*)d_ws) <= ws_size;

    dim3 blk(256);

    if (PS) {
        PackJob j0 = { gk,   gkp,  U3, KXM, 0 };
        PackJob j1 = { grk,  grkp, U3, U,   1920 };
        PackJob j2 = { Wtop, wtpp, U,  U,   1920 + 1536 };
        PackJob j3 = { Wbot, wbpp, U,  U,   1920 + 1536 + 512 };
        PackJob j4 = { memW, mwp,  U,  U,   1920 + 1536 + 512 + 512 };
        pack_w3_all<<<1920 + 1536 + 512 + 512 + 512, blk, 0, stream>>>(j0, j1, j2, j3, j4);
    }
    pack_w<<<(size_t)U * V / 8 / 256, blk, 0, stream>>>(fcW, fcWp, V, U);
    (void)hipMemcpyAsync(h, enc, (size_t)B * U * sizeof(float),
                         hipMemcpyDeviceToDevice, stream);

    if (PS) gemm_xe<true><<<dim3(U3 / 64, T), blk, 0, stream>>>(x, emb, gk, gkp, xe);
    else    gemm_xe<false><<<dim3(U3 / 64, T), blk, 0, stream>>>(x, emb, gk, gkp, xe);

    if (PS) gemm_keys<true><<<dim3(U / 128, B * S / 64), blk, 0, stream>>>(memory, memW, mwp, keys);
    else    gemm_keys<false><<<dim3(U / 128, B * S / 64), blk, 0, stream>>>(memory, memW, mwp, keys);

    if (PS) gemm_keys<true><<<dim3(U / 128, B * S / 64), blk, 0, stream>>>(memory, Wbot, wbpp, memV);
    else    gemm_keys<false><<<dim3(U / 128, B * S / 64), blk, 0, stream>>>(memory, Wbot, wbpp, memV);

    GemmJob job_hm = { h, grk, grkp, (size_t)U * U3, 0, 32, hm_part, U };

    for (int t = 0; t < T; t++) {
        GemmJob job_xm = { attnv_all + (size_t)(t - 1) * B * U, gk, gkp,
                           (size_t)KXM * U3, 8, 40, xm_part, U };
        // 1) hm (+xm) — R14-proven ks=8, nkc=4
        dim3 g1(U3 / 64, 8, t > 0 ? 2 : 1);
        if (PS) gemm6_ks2<true><<<g1, blk, 0, stream>>>(job_hm, job_xm, U3, 4);
        else    gemm6_ks2<false><<<g1, blk, 0, stream>>>(job_hm, job_xm, U3, 4);
        // 2) gates at 256 blocks (full-BW partial sums)
        gates_k<<<B * U / 256, blk, 0, stream>>>(
            xe + (size_t)t * B * U3, xm_part, hm_part, gb, h, t > 0 ? 1 : 0);
        // 3) scores (1280) || ah = h@Wtop (128) — both depend only on h
        if (PS) sc_ah<true><<<B * S / 4 + 128, blk, 0, stream>>>(
            h, keys, scores, Wtop, wtpp, ah_part);
        else    sc_ah<false><<<B * S / 4 + 128, blk, 0, stream>>>(
            h, keys, scores, Wtop, wtpp, ah_part);
        // 4) attnv = sum8(ah) + softmax(scores)@memV
        pnmv_sm<<<dim3(B, U / 256), blk, 0, stream>>>(
            ah_part, scores, memV, attnv_all + (size_t)t * B * U);
    }

    // all logits at once: [T*64, U] @ [U, V] + fcb (M64, XCD-pinned)
    gemm_fcB<<<32 * T * 8, blk, 0, stream>>>(attnv_all, fcWp, fcb, out);
}

// Round 20
// 1062.025 us; speedup vs baseline: 10.3708x; 1.0561x over previous
//
#include <hip/hip_runtime.h>
#include <hip/hip_bf16.h>
#include <math.h>

#define B 64
#define T 19
#define S 80
#define V 32000
#define E 256
#define U 1024
#define U3 (3*U)        // 3072
#define KXM (E+U)       // 1280

typedef unsigned short ushortT;
typedef __attribute__((ext_vector_type(8))) __bf16 bf16x8;
typedef __attribute__((ext_vector_type(4))) float f32x4;

__device__ __forceinline__ ushortT f2bf(float f) {
    unsigned int u = __float_as_uint(f);
    u = (u + 0x7FFF + ((u >> 16) & 1)) >> 16;   // RNE
    return (ushortT)u;
}
__device__ __forceinline__ float bf2f(ushortT u) {
    return __uint_as_float(((unsigned int)u) << 16);
}
__device__ __forceinline__ void split3(float v, ushortT& hi, ushortT& mid, ushortT& lo) {
    hi = f2bf(v);
    float r1 = v - bf2f(hi);
    mid = f2bf(r1);
    float r2 = r1 - bf2f(mid);
    lo = f2bf(r2);
}

// ---------------------------------------------------------------------------
// Merged pre-split weight pack: 5 matrices in one launch.
// ---------------------------------------------------------------------------
struct PackJob { const float* W; ushortT* Wp; int N; int K; int blk0; };

__global__ __launch_bounds__(256) void pack_w3_all(
    PackJob j0, PackJob j1, PackJob j2, PackJob j3, PackJob j4)
{
    int bid = blockIdx.x;
    PackJob J = j4;
    if (bid < j1.blk0) J = j0;
    else if (bid < j2.blk0) J = j1;
    else if (bid < j3.blk0) J = j2;
    else if (bid < j4.blk0) J = j3;

    int idx = (bid - J.blk0) * 256 + threadIdx.x;
    int lane = idx & 63;
    int t = idx >> 6;
    int KC = J.K >> 5;
    int ntile = t / KC, kc = t - ntile * KC;
    int col = ntile * 16 + (lane & 15);
    int krow = kc * 32 + (lane >> 4) * 8;
    ushortT hi[8], mi[8], lo[8];
    #pragma unroll
    for (int i = 0; i < 8; i++)
        split3(J.W[(size_t)(krow + i) * J.N + col], hi[i], mi[i], lo[i]);
    size_t ps = (size_t)J.K * J.N;
    *(uint4*)(J.Wp + (size_t)idx * 8)          = *(uint4*)hi;
    *(uint4*)(J.Wp + ps + (size_t)idx * 8)     = *(uint4*)mi;
    *(uint4*)(J.Wp + 2 * ps + (size_t)idx * 8) = *(uint4*)lo;
}

// fc pack (single bf16, proven)
__global__ __launch_bounds__(256) void pack_w(
    const float* __restrict__ W, ushortT* __restrict__ Wp, int N, int K)
{
    int idx = blockIdx.x * 256 + threadIdx.x;
    int lane = idx & 63;
    int t = idx >> 6;
    int KC = K >> 5;
    int ntile = t / KC, kc = t - ntile * KC;
    int col = ntile * 16 + (lane & 15);
    int krow = kc * 32 + (lane >> 4) * 8;
    ushortT tmp[8];
    #pragma unroll
    for (int i = 0; i < 8; i++)
        tmp[i] = f2bf(W[(size_t)(krow + i) * N + col]);
    *(uint4*)(Wp + (size_t)idx * 8) = *(uint4*)tmp;
}

// ---------------------------------------------------------------------------
// split6 GEMM body (shared).
// ---------------------------------------------------------------------------
struct GemmJob {
    const float*   A;
    const float*   W;
    const ushortT* Wp;
    unsigned long long ps;
    int kc_base;
    int KCtot;
    float* Cpart;
    int lda;
};

template<bool PRESPLIT>
__device__ __forceinline__ void gemm6_body(
    const GemmJob& J, int xblk, int ks, int nkc, int N,
    ushortT* Ahi, ushortT* Amid, ushortT* Alo)
{
    const int tid = threadIdx.x;
    const int lane = tid & 63;
    const int wave = tid >> 6;
    const int ntile = xblk * 4 + wave;
    const int col = ntile * 16 + (lane & 15);
    const int kfrag = (lane >> 4) * 8;

    f32x4 acc[4] = {};
    const int arow = (tid >> 6) * 16 + (tid & 15);
    const int kgof = ((tid >> 4) & 3) * 8;

    for (int c = 0; c < nkc; c++) {
        const int kc = ks * nkc + c;
        const float* ar = J.A + (size_t)arow * J.lda + kc * 32 + kgof;
        float av[8];
        *(float4*)(av)     = *(const float4*)(ar);
        *(float4*)(av + 4) = *(const float4*)(ar + 4);
        ushortT thi[8], tmi[8], tlo[8];
        #pragma unroll
        for (int i = 0; i < 8; i++) split3(av[i], thi[i], tmi[i], tlo[i]);
        ((uint4*)Ahi)[tid]  = *(const uint4*)thi;
        ((uint4*)Amid)[tid] = *(const uint4*)tmi;
        ((uint4*)Alo)[tid]  = *(const uint4*)tlo;

        bf16x8 bh, bm, bl;
        if constexpr (PRESPLIT) {
            size_t fi = (((size_t)ntile * J.KCtot + (J.kc_base + kc)) * 64 + lane) * 8;
            bh = *(const bf16x8*)(J.Wp + fi);
            bm = *(const bf16x8*)(J.Wp + J.ps + fi);
            bl = *(const bf16x8*)(J.Wp + 2 * J.ps + fi);
        } else {
            const float* wp = J.W + (size_t)((J.kc_base + kc) * 32 + kfrag) * N + col;
            ushortT whi[8], wmi[8], wlo[8];
            #pragma unroll
            for (int i = 0; i < 8; i++)
                split3(wp[(size_t)i * N], whi[i], wmi[i], wlo[i]);
            bh = *(const bf16x8*)whi;
            bm = *(const bf16x8*)wmi;
            bl = *(const bf16x8*)wlo;
        }

        __syncthreads();
        #pragma unroll
        for (int mi = 0; mi < 4; mi++) {
            bf16x8 ah = *(const bf16x8*)(Ahi  + (mi * 64 + lane) * 8);
            bf16x8 am = *(const bf16x8*)(Amid + (mi * 64 + lane) * 8);
            bf16x8 al = *(const bf16x8*)(Alo  + (mi * 64 + lane) * 8);
            acc[mi] = __builtin_amdgcn_mfma_f32_16x16x32_bf16(ah, bh, acc[mi], 0, 0, 0);
            acc[mi] = __builtin_amdgcn_mfma_f32_16x16x32_bf16(am, bh, acc[mi], 0, 0, 0);
            acc[mi] = __builtin_amdgcn_mfma_f32_16x16x32_bf16(ah, bm, acc[mi], 0, 0, 0);
            acc[mi] = __builtin_amdgcn_mfma_f32_16x16x32_bf16(am, bm, acc[mi], 0, 0, 0);
            acc[mi] = __builtin_amdgcn_mfma_f32_16x16x32_bf16(al, bh, acc[mi], 0, 0, 0);
            acc[mi] = __builtin_amdgcn_mfma_f32_16x16x32_bf16(ah, bl, acc[mi], 0, 0, 0);
        }
        __syncthreads();
    }

    float* cp = J.Cpart + (size_t)ks * 64 * N;
    #pragma unroll
    for (int mi = 0; mi < 4; mi++) {
        #pragma unroll
        for (int r = 0; r < 4; r++) {
            int m = mi * 16 + (lane >> 4) * 4 + r;
            cp[(size_t)m * N + col] = acc[mi][r];
        }
    }
}

// classic kernel wrapper (2-job fusion via blockIdx.z)
template<bool PRESPLIT>
__global__ __launch_bounds__(256) void gemm6_ks2(
    GemmJob j0, GemmJob j1, int N, int nkc)
{
    __shared__ __align__(16) ushortT Ahi[2048];
    __shared__ __align__(16) ushortT Amid[2048];
    __shared__ __align__(16) ushortT Alo[2048];
    const GemmJob J = blockIdx.z ? j1 : j0;
    gemm6_body<PRESPLIT>(J, blockIdx.x, blockIdx.y, nkc, N, Ahi, Amid, Alo);
}

// ---------------------------------------------------------------------------
// Fused keys+memV GEMM: C1 = A@W1, C2 = A@W2 ([B*S,1024]@[1024,1024] each),
// sharing the A staging/split (A = memory read ONCE). grid (U/128, B*S/64).
// Per wave: 2 n-tiles x 2 outputs -> 24 MFMA per A-stage.
// ---------------------------------------------------------------------------
template<bool PRESPLIT>
__global__ __launch_bounds__(256) void gemm_kv(
    const float* __restrict__ A,
    const float* __restrict__ W1, const ushortT* __restrict__ Wp1,
    const float* __restrict__ W2, const ushortT* __restrict__ Wp2,
    float* __restrict__ C1, float* __restrict__ C2)
{
    const int tid = threadIdx.x;
    const int lane = tid & 63;
    const int wave = tid >> 6;
    const int row0 = blockIdx.y * 64;
    const int nt0 = blockIdx.x * 8 + wave * 2;
    const int col0 = nt0 * 16 + (lane & 15);
    const int kfrag = (lane >> 4) * 8;

    __shared__ __align__(16) ushortT Ahi[2048];
    __shared__ __align__(16) ushortT Amid[2048];
    __shared__ __align__(16) ushortT Alo[2048];

    f32x4 acc1[2][4] = {};
    f32x4 acc2[2][4] = {};
    const int arow = row0 + (tid >> 6) * 16 + (tid & 15);
    const int kgof = ((tid >> 4) & 3) * 8;
    const size_t ps = (size_t)U * U;

    for (int kc = 0; kc < 32; kc++) {
        const float* ar = A + (size_t)arow * U + kc * 32 + kgof;
        float av[8];
        *(float4*)(av)     = *(const float4*)(ar);
        *(float4*)(av + 4) = *(const float4*)(ar + 4);
        ushortT thi[8], tmi[8], tlo[8];
        #pragma unroll
        for (int i = 0; i < 8; i++) split3(av[i], thi[i], tmi[i], tlo[i]);
        ((uint4*)Ahi)[tid]  = *(const uint4*)thi;
        ((uint4*)Amid)[tid] = *(const uint4*)tmi;
        ((uint4*)Alo)[tid]  = *(const uint4*)tlo;

        bf16x8 b1h[2], b1m[2], b1l[2], b2h[2], b2m[2], b2l[2];
        #pragma unroll
        for (int j = 0; j < 2; j++) {
            if constexpr (PRESPLIT) {
                size_t fi = (((size_t)(nt0 + j) * 32 + kc) * 64 + lane) * 8;
                b1h[j] = *(const bf16x8*)(Wp1 + fi);
                b1m[j] = *(const bf16x8*)(Wp1 + ps + fi);
                b1l[j] = *(const bf16x8*)(Wp1 + 2 * ps + fi);
                b2h[j] = *(const bf16x8*)(Wp2 + fi);
                b2m[j] = *(const bf16x8*)(Wp2 + ps + fi);
                b2l[j] = *(const bf16x8*)(Wp2 + 2 * ps + fi);
            } else {
                const float* wp1 = W1 + (size_t)(kc * 32 + kfrag) * U + col0 + j * 16;
                const float* wp2 = W2 + (size_t)(kc * 32 + kfrag) * U + col0 + j * 16;
                ushortT w1h[8], w1m[8], w1l[8], w2h[8], w2m[8], w2l[8];
                #pragma unroll
                for (int i = 0; i < 8; i++) {
                    split3(wp1[(size_t)i * U], w1h[i], w1m[i], w1l[i]);
                    split3(wp2[(size_t)i * U], w2h[i], w2m[i], w2l[i]);
                }
                b1h[j] = *(const bf16x8*)w1h; b1m[j] = *(const bf16x8*)w1m; b1l[j] = *(const bf16x8*)w1l;
                b2h[j] = *(const bf16x8*)w2h; b2m[j] = *(const bf16x8*)w2m; b2l[j] = *(const bf16x8*)w2l;
            }
        }

        __syncthreads();
        #pragma unroll
        for (int mi = 0; mi < 4; mi++) {
            bf16x8 ah = *(const bf16x8*)(Ahi  + (mi * 64 + lane) * 8);
            bf16x8 am = *(const bf16x8*)(Amid + (mi * 64 + lane) * 8);
            bf16x8 al = *(const bf16x8*)(Alo  + (mi * 64 + lane) * 8);
            #pragma unroll
            for (int j = 0; j < 2; j++) {
                acc1[j][mi] = __builtin_amdgcn_mfma_f32_16x16x32_bf16(ah, b1h[j], acc1[j][mi], 0, 0, 0);
                acc1[j][mi] = __builtin_amdgcn_mfma_f32_16x16x32_bf16(am, b1h[j], acc1[j][mi], 0, 0, 0);
                acc1[j][mi] = __builtin_amdgcn_mfma_f32_16x16x32_bf16(ah, b1m[j], acc1[j][mi], 0, 0, 0);
                acc1[j][mi] = __builtin_amdgcn_mfma_f32_16x16x32_bf16(am, b1m[j], acc1[j][mi], 0, 0, 0);
                acc1[j][mi] = __builtin_amdgcn_mfma_f32_16x16x32_bf16(al, b1h[j], acc1[j][mi], 0, 0, 0);
                acc1[j][mi] = __builtin_amdgcn_mfma_f32_16x16x32_bf16(ah, b1l[j], acc1[j][mi], 0, 0, 0);
                acc2[j][mi] = __builtin_amdgcn_mfma_f32_16x16x32_bf16(ah, b2h[j], acc2[j][mi], 0, 0, 0);
                acc2[j][mi] = __builtin_amdgcn_mfma_f32_16x16x32_bf16(am, b2h[j], acc2[j][mi], 0, 0, 0);
                acc2[j][mi] = __builtin_amdgcn_mfma_f32_16x16x32_bf16(ah, b2m[j], acc2[j][mi], 0, 0, 0);
                acc2[j][mi] = __builtin_amdgcn_mfma_f32_16x16x32_bf16(am, b2m[j], acc2[j][mi], 0, 0, 0);
                acc2[j][mi] = __builtin_amdgcn_mfma_f32_16x16x32_bf16(al, b2h[j], acc2[j][mi], 0, 0, 0);
                acc2[j][mi] = __builtin_amdgcn_mfma_f32_16x16x32_bf16(ah, b2l[j], acc2[j][mi], 0, 0, 0);
            }
        }
        __syncthreads();
    }

    #pragma unroll
    for (int mi = 0; mi < 4; mi++) {
        #pragma unroll
        for (int r = 0; r < 4; r++) {
            int m = row0 + mi * 16 + (lane >> 4) * 4 + r;
            #pragma unroll
            for (int j = 0; j < 2; j++) {
                C1[(size_t)m * U + col0 + j * 16] = acc1[j][mi][r];
                C2[(size_t)m * U + col0 + j * 16] = acc2[j][mi][r];
            }
        }
    }
}

// ---------------------------------------------------------------------------
// xe[t] = emb[x[:,t]] @ gk[0:256,:]   grid (U3/64, T)
// ---------------------------------------------------------------------------
template<bool PRESPLIT>
__global__ __launch_bounds__(256) void gemm_xe(
    const int* __restrict__ x, const float* __restrict__ emb,
    const float* __restrict__ gk, const ushortT* __restrict__ gkp,
    float* __restrict__ xe)
{
    const int tid = threadIdx.x;
    const int lane = tid & 63;
    const int wave = tid >> 6;
    const int t = blockIdx.y;
    const int ntile = blockIdx.x * 4 + wave;
    const int col = ntile * 16 + (lane & 15);
    const int kfrag = (lane >> 4) * 8;

    __shared__ __align__(16) ushortT Ahi[2048];
    __shared__ __align__(16) ushortT Amid[2048];
    __shared__ __align__(16) ushortT Alo[2048];

    f32x4 acc[4] = {};
    const int b = (tid >> 6) * 16 + (tid & 15);
    const int tok = x[b * T + t];
    const int kgof = ((tid >> 4) & 3) * 8;
    const size_t ps = (size_t)KXM * U3;

    for (int kc = 0; kc < E / 32; kc++) {
        const float* ar = emb + (size_t)tok * E + kc * 32 + kgof;
        float av[8];
        *(float4*)(av)     = *(const float4*)(ar);
        *(float4*)(av + 4) = *(const float4*)(ar + 4);
        ushortT thi[8], tmi[8], tlo[8];
        #pragma unroll
        for (int i = 0; i < 8; i++) split3(av[i], thi[i], tmi[i], tlo[i]);
        ((uint4*)Ahi)[tid]  = *(const uint4*)thi;
        ((uint4*)Amid)[tid] = *(const uint4*)tmi;
        ((uint4*)Alo)[tid]  = *(const uint4*)tlo;

        bf16x8 bh, bm, bl;
        if constexpr (PRESPLIT) {
            size_t fi = (((size_t)ntile * 40 + kc) * 64 + lane) * 8;   // gk KCtot=40
            bh = *(const bf16x8*)(gkp + fi);
            bm = *(const bf16x8*)(gkp + ps + fi);
            bl = *(const bf16x8*)(gkp + 2 * ps + fi);
        } else {
            const float* wp = gk + (size_t)(kc * 32 + kfrag) * U3 + col;
            ushortT whi[8], wmi[8], wlo[8];
            #pragma unroll
            for (int i = 0; i < 8; i++)
                split3(wp[(size_t)i * U3], whi[i], wmi[i], wlo[i]);
            bh = *(const bf16x8*)whi;
            bm = *(const bf16x8*)wmi;
            bl = *(const bf16x8*)wlo;
        }

        __syncthreads();
        #pragma unroll
        for (int mi = 0; mi < 4; mi++) {
            bf16x8 ah = *(const bf16x8*)(Ahi  + (mi * 64 + lane) * 8);
            bf16x8 am = *(const bf16x8*)(Amid + (mi * 64 + lane) * 8);
            bf16x8 al = *(const bf16x8*)(Alo  + (mi * 64 + lane) * 8);
            acc[mi] = __builtin_amdgcn_mfma_f32_16x16x32_bf16(ah, bh, acc[mi], 0, 0, 0);
            acc[mi] = __builtin_amdgcn_mfma_f32_16x16x32_bf16(am, bh, acc[mi], 0, 0, 0);
            acc[mi] = __builtin_amdgcn_mfma_f32_16x16x32_bf16(ah, bm, acc[mi], 0, 0, 0);
            acc[mi] = __builtin_amdgcn_mfma_f32_16x16x32_bf16(am, bm, acc[mi], 0, 0, 0);
            acc[mi] = __builtin_amdgcn_mfma_f32_16x16x32_bf16(al, bh, acc[mi], 0, 0, 0);
            acc[mi] = __builtin_amdgcn_mfma_f32_16x16x32_bf16(ah, bl, acc[mi], 0, 0, 0);
        }
        __syncthreads();
    }

    #pragma unroll
    for (int mi = 0; mi < 4; mi++) {
        #pragma unroll
        for (int r = 0; r < 4; r++) {
            int m = mi * 16 + (lane >> 4) * 4 + r;
            xe[((size_t)t * 64 + m) * U3 + col] = acc[mi][r];
        }
    }
}

// ---------------------------------------------------------------------------
// Batched fc GEMM (R10 M64 + bf16 A): XCD-pinned t-major.
// A is pre-rounded bf16 (written by pnmv_sm) — bit-identical to inline f2bf.
// ---------------------------------------------------------------------------
__global__ __launch_bounds__(256) void gemm_fcB(
    const ushortT* __restrict__ A, const ushortT* __restrict__ Wp,
    const float* __restrict__ bias, float* __restrict__ C)
{
    const int xcd = blockIdx.x & 7;
    const int rem = blockIdx.x >> 3;        // g*19 + t
    const int g = rem / T;
    const int tg = rem - g * T;
    const int strip = g * 8 + xcd;
    if (strip >= V / 128) return;

    const int tid = threadIdx.x;
    const int lane = tid & 63;
    const int wave = tid >> 6;
    const int nt0 = strip * 8 + wave * 2;
    const int col0 = nt0 * 16 + (lane & 15);

    __shared__ __align__(16) ushortT As[2][2048];

    f32x4 acc[2][4] = {};
    const int arow = (tid >> 6) * 16 + (tid & 15);
    const ushortT* At = A + (size_t)tg * 64 * U;
    float* Ct = C + (size_t)tg * V;
    const int kgof = ((tid >> 4) & 3) * 8;

    for (int it = 0; it < 16; it++) {
        #pragma unroll
        for (int c = 0; c < 2; c++) {
            const ushortT* ar = At + (size_t)arow * U + (it * 2 + c) * 32 + kgof;
            ((uint4*)As[c])[tid] = *(const uint4*)ar;
        }
        bf16x8 b[2][2];
        #pragma unroll
        for (int c = 0; c < 2; c++)
            #pragma unroll
            for (int j = 0; j < 2; j++)
                b[c][j] = *(const bf16x8*)(Wp +
                    (((size_t)(nt0 + j) * 32 + it * 2 + c) * 64 + lane) * 8);
        __syncthreads();
        #pragma unroll
        for (int c = 0; c < 2; c++) {
            #pragma unroll
            for (int mi = 0; mi < 4; mi++) {
                bf16x8 a = *(const bf16x8*)(As[c] + (mi * 64 + lane) * 8);
                #pragma unroll
                for (int j = 0; j < 2; j++)
                    acc[j][mi] = __builtin_amdgcn_mfma_f32_16x16x32_bf16(a, b[c][j], acc[j][mi], 0, 0, 0);
            }
        }
        __syncthreads();
    }

    #pragma unroll
    for (int j = 0; j < 2; j++) {
        const float bv = bias[col0 + j * 16];
        #pragma unroll
        for (int mi = 0; mi < 4; mi++) {
            #pragma unroll
            for (int r = 0; r < 4; r++) {
                int m = mi * 16 + (lane >> 4) * 4 + r;
                __builtin_nontemporal_store(acc[j][mi][r] + bv,
                    &Ct[(size_t)m * (T * V) + col0 + j * 16]);
            }
        }
    }
}

// ---------------------------------------------------------------------------
// GRU gates at full parallelism: grid B*U/256 = 256 blocks (R19-proven).
// ---------------------------------------------------------------------------
__global__ __launch_bounds__(256) void gates_k(
    const float* __restrict__ xe_t, const float* __restrict__ xm_part,
    const float* __restrict__ hm_part, const float* __restrict__ gb,
    float* __restrict__ h, int use_xm)
{
    int idx = blockIdx.x * 256 + threadIdx.x;   // B*U
    int b = idx >> 10, u = idx & (U - 1);
    float xv[3], hv[3];
    #pragma unroll
    for (int g = 0; g < 3; g++) {
        int j = g * U + u;
        float xs = xe_t[(size_t)b * U3 + j] + gb[j];
        float hsum = gb[U3 + j];
        if (use_xm) {
            #pragma unroll
            for (int p = 0; p < 8; p++)
                xs += xm_part[((size_t)p * 64 + b) * U3 + j];
        }
        #pragma unroll
        for (int p = 0; p < 8; p++)
            hsum += hm_part[((size_t)p * 64 + b) * U3 + j];
        xv[g] = xs; hv[g] = hsum;
    }
    float z = 1.f / (1.f + expf(-(xv[0] + hv[0])));
    float r = 1.f / (1.f + expf(-(xv[1] + hv[1])));
    float hh = tanhf(xv[2] + r * hv[2]);
    h[idx] = z * h[idx] + (1.f - z) * hh;
}

// ---------------------------------------------------------------------------
// Co-launched scores (1280 blocks, wave per (b,s)) + ah = h@Wtop (128 blocks).
// (R19-proven.)
// ---------------------------------------------------------------------------
template<bool PRESPLIT>
__global__ __launch_bounds__(256) void sc_ah(
    const float* __restrict__ h, const float* __restrict__ keys,
    float* __restrict__ scores,
    const float* __restrict__ Wtop, const ushortT* __restrict__ wtpp,
    float* __restrict__ ah_part)
{
    __shared__ __align__(16) ushortT Ahi[2048];
    __shared__ __align__(16) ushortT Amid[2048];
    __shared__ __align__(16) ushortT Alo[2048];

    const int bid = blockIdx.x;
    if (bid < B * S / 4) {
        int gw = bid * 4 + (threadIdx.x >> 6);
        int lane = threadIdx.x & 63;
        int b = gw / S, s = gw - b * S;
        const float* kr = keys + ((size_t)b * S + s) * U;
        const float* hr = h + (size_t)b * U;
        float acc = 0.f;
        #pragma unroll
        for (int c = 0; c < 4; c++) {
            int off = c * 256 + lane * 4;
            float4 kv = *(const float4*)(kr + off);
            float4 hv = *(const float4*)(hr + off);
            acc += kv.x * hv.x + kv.y * hv.y + kv.z * hv.z + kv.w * hv.w;
        }
        #pragma unroll
        for (int off = 32; off > 0; off >>= 1) acc += __shfl_down(acc, off);
        if (lane == 0) scores[gw] = acc;
    } else {
        int r = bid - B * S / 4;       // 0..127: 16 x-tiles x 8 ks
        GemmJob job = { h, Wtop, wtpp, (size_t)U * U, 0, 32, ah_part, U };
        gemm6_body<PRESPLIT>(job, r & 15, r >> 4, 4, U, Ahi, Amid, Alo);
    }
}

// ---------------------------------------------------------------------------
// pnmv + inline softmax: attnv = sum8(ah_part) + softmax(scores)@memV.
// Writes fp32 (for xm GEMM) and bf16 (for fcB; f2bf here == fcB's old inline
// conversion -> bit-identical logits). grid (B, U/256).
// ---------------------------------------------------------------------------
__global__ __launch_bounds__(256) void pnmv_sm(
    const float* __restrict__ ah_part, const float* __restrict__ scores,
    const float* __restrict__ memV, float* __restrict__ dst,
    ushortT* __restrict__ dst_bf)
{
    const int b = blockIdx.x;
    const int u = blockIdx.y * 256 + threadIdx.x;
    __shared__ float p[S];
    __shared__ float pl[S];
    if (threadIdx.x < S) p[threadIdx.x] = scores[b * S + threadIdx.x];
    __syncthreads();
    float m = -1e30f;
    #pragma unroll 8
    for (int s = 0; s < S; s++) m = fmaxf(m, p[s]);
    float sum = 0.f;
    #pragma unroll 8
    for (int s = 0; s < S; s++) sum += expf(p[s] - m);
    if (threadIdx.x < S) pl[threadIdx.x] = expf(p[threadIdx.x] - m) / sum;
    __syncthreads();
    float acc = 0.f;
    #pragma unroll
    for (int pp = 0; pp < 8; pp++)
        acc += ah_part[((size_t)pp * 64 + b) * U + u];
    #pragma unroll 8
    for (int s = 0; s < S; s++)
        acc += pl[s] * memV[((size_t)b * S + s) * U + u];
    dst[(size_t)b * U + u] = acc;
    dst_bf[(size_t)b * U + u] = f2bf(acc);
}

// ---------------------------------------------------------------------------
extern "C" void kernel_launch(void* const* d_in, const int* in_sizes, int n_in,
                              void* d_out, int out_size, void* d_ws, size_t ws_size,
                              hipStream_t stream)
{
    const int*   x      = (const int*)  d_in[0];
    const float* enc    = (const float*)d_in[1];
    const float* memory = (const float*)d_in[2];
    const float* emb    = (const float*)d_in[3];
    const float* gk     = (const float*)d_in[4];
    const float* grk    = (const float*)d_in[5];
    const float* gb     = (const float*)d_in[6];
    const float* memW   = (const float*)d_in[7];
    const float* attnW  = (const float*)d_in[8];
    const float* fcW    = (const float*)d_in[9];
    const float* fcb    = (const float*)d_in[10];
    float* out = (float*)d_out;

    const float* Wtop = attnW;
    const float* Wbot = attnW + (size_t)U * U;

    char* p = (char*)d_ws;
    auto alloc = [&](size_t bytes) { char* r = p; p += (bytes + 255) & ~(size_t)255; return r; };
    ushortT* fcWp      = (ushortT*)alloc((size_t)U * V * 2);
    float*   keys      = (float*)  alloc((size_t)B * S * U * 4);
    float*   memV      = (float*)  alloc((size_t)B * S * U * 4);
    float*   xe        = (float*)  alloc((size_t)T * B * U3 * 4);
    float*   xm_part   = (float*)  alloc((size_t)8 * B * U3 * 4);
    float*   hm_part   = (float*)  alloc((size_t)8 * B * U3 * 4);
    float*   ah_part   = (float*)  alloc((size_t)8 * B * U * 4);
    float*   h         = (float*)  alloc((size_t)B * U * 4);
    float*   attnv_all = (float*)  alloc((size_t)T * B * U * 4);
    ushortT* attnv_bf  = (ushortT*)alloc((size_t)T * B * U * 2);
    float*   scores    = (float*)  alloc((size_t)B * S * 4);
    ushortT* gkp       = (ushortT*)alloc((size_t)KXM * U3 * 2 * 3);
    ushortT* grkp      = (ushortT*)alloc((size_t)U * U3 * 2 * 3);
    ushortT* wtpp      = (ushortT*)alloc((size_t)U * U * 2 * 3);
    ushortT* wbpp      = (ushortT*)alloc((size_t)U * U * 2 * 3);
    ushortT* mwp       = (ushortT*)alloc((size_t)U * U * 2 * 3);
    const bool PS = (size_t)(p - (char*)d_ws) <= ws_size;

    dim3 blk(256);

    if (PS) {
        PackJob j0 = { gk,   gkp,  U3, KXM, 0 };
        PackJob j1 = { grk,  grkp, U3, U,   1920 };
        PackJob j2 = { Wtop, wtpp, U,  U,   1920 + 1536 };
        PackJob j3 = { Wbot, wbpp, U,  U,   1920 + 1536 + 512 };
        PackJob j4 = { memW, mwp,  U,  U,   1920 + 1536 + 512 + 512 };
        pack_w3_all<<<1920 + 1536 + 512 + 512 + 512, blk, 0, stream>>>(j0, j1, j2, j3, j4);
    }
    pack_w<<<(size_t)U * V / 8 / 256, blk, 0, stream>>>(fcW, fcWp, V, U);
    (void)hipMemcpyAsync(h, enc, (size_t)B * U * sizeof(float),
                         hipMemcpyDeviceToDevice, stream);

    if (PS) gemm_xe<true><<<dim3(U3 / 64, T), blk, 0, stream>>>(x, emb, gk, gkp, xe);
    else    gemm_xe<false><<<dim3(U3 / 64, T), blk, 0, stream>>>(x, emb, gk, gkp, xe);

    // keys = memory@memW and memV = memory@Wbot in ONE pass over memory
    if (PS) gemm_kv<true><<<dim3(U / 128, B * S / 64), blk, 0, stream>>>(
        memory, memW, mwp, Wbot, wbpp, keys, memV);
    else    gemm_kv<false><<<dim3(U / 128, B * S / 64), blk, 0, stream>>>(
        memory, memW, mwp, Wbot, wbpp, keys, memV);

    GemmJob job_hm = { h, grk, grkp, (size_t)U * U3, 0, 32, hm_part, U };

    for (int t = 0; t < T; t++) {
        GemmJob job_xm = { attnv_all + (size_t)(t - 1) * B * U, gk, gkp,
                           (size_t)KXM * U3, 8, 40, xm_part, U };
        // 1) hm (+xm) — R14-proven ks=8, nkc=4
        dim3 g1(U3 / 64, 8, t > 0 ? 2 : 1);
        if (PS) gemm6_ks2<true><<<g1, blk, 0, stream>>>(job_hm, job_xm, U3, 4);
        else    gemm6_ks2<false><<<g1, blk, 0, stream>>>(job_hm, job_xm, U3, 4);
        // 2) gates at 256 blocks
        gates_k<<<B * U / 256, blk, 0, stream>>>(
            xe + (size_t)t * B * U3, xm_part, hm_part, gb, h, t > 0 ? 1 : 0);
        // 3) scores (1280) || ah = h@Wtop (128)
        if (PS) sc_ah<true><<<B * S / 4 + 128, blk, 0, stream>>>(
            h, keys, scores, Wtop, wtpp, ah_part);
        else    sc_ah<false><<<B * S / 4 + 128, blk, 0, stream>>>(
            h, keys, scores, Wtop, wtpp, ah_part);
        // 4) attnv = sum8(ah) + softmax(scores)@memV  (fp32 + bf16 copies)
        pnmv_sm<<<dim3(B, U / 256), blk, 0, stream>>>(
            ah_part, scores, memV, attnv_all + (size_t)t * B * U,
            attnv_bf + (size_t)t * B * U);
    }

    // all logits at once: bf16 A [T*64, U] @ packed fcW + fcb (M64, XCD-pinned)
    gemm_fcB<<<32 * T * 8, blk, 0, stream>>>(attnv_bf, fcWp, fcb, out);
}

// Round 21
// 1059.650 us; speedup vs baseline: 10.3940x; 1.0022x over previous
//
#include <hip/hip_runtime.h>
#include <hip/hip_bf16.h>
#include <math.h>

#define B 64
#define T 19
#define S 80
#define V 32000
#define E 256
#define U 1024
#define U3 (3*U)        // 3072
#define KXM (E+U)       // 1280

typedef unsigned short ushortT;
typedef __attribute__((ext_vector_type(8))) __bf16 bf16x8;
typedef __attribute__((ext_vector_type(4))) float f32x4;

__device__ __forceinline__ ushortT f2bf(float f) {
    unsigned int u = __float_as_uint(f);
    u = (u + 0x7FFF + ((u >> 16) & 1)) >> 16;   // RNE
    return (ushortT)u;
}
__device__ __forceinline__ float bf2f(ushortT u) {
    return __uint_as_float(((unsigned int)u) << 16);
}
__device__ __forceinline__ void split3(float v, ushortT& hi, ushortT& mid, ushortT& lo) {
    hi = f2bf(v);
    float r1 = v - bf2f(hi);
    mid = f2bf(r1);
    float r2 = r1 - bf2f(mid);
    lo = f2bf(r2);
}

// ---------------------------------------------------------------------------
// Merged pre-split weight pack: 5 matrices in one launch.
// ---------------------------------------------------------------------------
struct PackJob { const float* W; ushortT* Wp; int N; int K; int blk0; };

__global__ __launch_bounds__(256) void pack_w3_all(
    PackJob j0, PackJob j1, PackJob j2, PackJob j3, PackJob j4)
{
    int bid = blockIdx.x;
    PackJob J = j4;
    if (bid < j1.blk0) J = j0;
    else if (bid < j2.blk0) J = j1;
    else if (bid < j3.blk0) J = j2;
    else if (bid < j4.blk0) J = j3;

    int idx = (bid - J.blk0) * 256 + threadIdx.x;
    int lane = idx & 63;
    int t = idx >> 6;
    int KC = J.K >> 5;
    int ntile = t / KC, kc = t - ntile * KC;
    int col = ntile * 16 + (lane & 15);
    int krow = kc * 32 + (lane >> 4) * 8;
    ushortT hi[8], mi[8], lo[8];
    #pragma unroll
    for (int i = 0; i < 8; i++)
        split3(J.W[(size_t)(krow + i) * J.N + col], hi[i], mi[i], lo[i]);
    size_t ps = (size_t)J.K * J.N;
    *(uint4*)(J.Wp + (size_t)idx * 8)          = *(uint4*)hi;
    *(uint4*)(J.Wp + ps + (size_t)idx * 8)     = *(uint4*)mi;
    *(uint4*)(J.Wp + 2 * ps + (size_t)idx * 8) = *(uint4*)lo;
}

// fc pack (single bf16, proven)
__global__ __launch_bounds__(256) void pack_w(
    const float* __restrict__ W, ushortT* __restrict__ Wp, int N, int K)
{
    int idx = blockIdx.x * 256 + threadIdx.x;
    int lane = idx & 63;
    int t = idx >> 6;
    int KC = K >> 5;
    int ntile = t / KC, kc = t - ntile * KC;
    int col = ntile * 16 + (lane & 15);
    int krow = kc * 32 + (lane >> 4) * 8;
    ushortT tmp[8];
    #pragma unroll
    for (int i = 0; i < 8; i++)
        tmp[i] = f2bf(W[(size_t)(krow + i) * N + col]);
    *(uint4*)(Wp + (size_t)idx * 8) = *(uint4*)tmp;
}

// ---------------------------------------------------------------------------
// split6 GEMM body (shared).
// ---------------------------------------------------------------------------
struct GemmJob {
    const float*   A;
    const float*   W;
    const ushortT* Wp;
    unsigned long long ps;
    int kc_base;
    int KCtot;
    float* Cpart;
    int lda;
};

template<bool PRESPLIT>
__device__ __forceinline__ void gemm6_body(
    const GemmJob& J, int xblk, int ks, int nkc, int N,
    ushortT* Ahi, ushortT* Amid, ushortT* Alo)
{
    const int tid = threadIdx.x;
    const int lane = tid & 63;
    const int wave = tid >> 6;
    const int ntile = xblk * 4 + wave;
    const int col = ntile * 16 + (lane & 15);
    const int kfrag = (lane >> 4) * 8;

    f32x4 acc[4] = {};
    const int arow = (tid >> 6) * 16 + (tid & 15);
    const int kgof = ((tid >> 4) & 3) * 8;

    for (int c = 0; c < nkc; c++) {
        const int kc = ks * nkc + c;
        const float* ar = J.A + (size_t)arow * J.lda + kc * 32 + kgof;
        float av[8];
        *(float4*)(av)     = *(const float4*)(ar);
        *(float4*)(av + 4) = *(const float4*)(ar + 4);
        ushortT thi[8], tmi[8], tlo[8];
        #pragma unroll
        for (int i = 0; i < 8; i++) split3(av[i], thi[i], tmi[i], tlo[i]);
        ((uint4*)Ahi)[tid]  = *(const uint4*)thi;
        ((uint4*)Amid)[tid] = *(const uint4*)tmi;
        ((uint4*)Alo)[tid]  = *(const uint4*)tlo;

        bf16x8 bh, bm, bl;
        if constexpr (PRESPLIT) {
            size_t fi = (((size_t)ntile * J.KCtot + (J.kc_base + kc)) * 64 + lane) * 8;
            bh = *(const bf16x8*)(J.Wp + fi);
            bm = *(const bf16x8*)(J.Wp + J.ps + fi);
            bl = *(const bf16x8*)(J.Wp + 2 * J.ps + fi);
        } else {
            const float* wp = J.W + (size_t)((J.kc_base + kc) * 32 + kfrag) * N + col;
            ushortT whi[8], wmi[8], wlo[8];
            #pragma unroll
            for (int i = 0; i < 8; i++)
                split3(wp[(size_t)i * N], whi[i], wmi[i], wlo[i]);
            bh = *(const bf16x8*)whi;
            bm = *(const bf16x8*)wmi;
            bl = *(const bf16x8*)wlo;
        }

        __syncthreads();
        #pragma unroll
        for (int mi = 0; mi < 4; mi++) {
            bf16x8 ah = *(const bf16x8*)(Ahi  + (mi * 64 + lane) * 8);
            bf16x8 am = *(const bf16x8*)(Amid + (mi * 64 + lane) * 8);
            bf16x8 al = *(const bf16x8*)(Alo  + (mi * 64 + lane) * 8);
            acc[mi] = __builtin_amdgcn_mfma_f32_16x16x32_bf16(ah, bh, acc[mi], 0, 0, 0);
            acc[mi] = __builtin_amdgcn_mfma_f32_16x16x32_bf16(am, bh, acc[mi], 0, 0, 0);
            acc[mi] = __builtin_amdgcn_mfma_f32_16x16x32_bf16(ah, bm, acc[mi], 0, 0, 0);
            acc[mi] = __builtin_amdgcn_mfma_f32_16x16x32_bf16(am, bm, acc[mi], 0, 0, 0);
            acc[mi] = __builtin_amdgcn_mfma_f32_16x16x32_bf16(al, bh, acc[mi], 0, 0, 0);
            acc[mi] = __builtin_amdgcn_mfma_f32_16x16x32_bf16(ah, bl, acc[mi], 0, 0, 0);
        }
        __syncthreads();
    }

    float* cp = J.Cpart + (size_t)ks * 64 * N;
    #pragma unroll
    for (int mi = 0; mi < 4; mi++) {
        #pragma unroll
        for (int r = 0; r < 4; r++) {
            int m = mi * 16 + (lane >> 4) * 4 + r;
            cp[(size_t)m * N + col] = acc[mi][r];
        }
    }
}

// classic kernel wrapper (2-job fusion via blockIdx.z)
template<bool PRESPLIT>
__global__ __launch_bounds__(256) void gemm6_ks2(
    GemmJob j0, GemmJob j1, int N, int nkc)
{
    __shared__ __align__(16) ushortT Ahi[2048];
    __shared__ __align__(16) ushortT Amid[2048];
    __shared__ __align__(16) ushortT Alo[2048];
    const GemmJob J = blockIdx.z ? j1 : j0;
    gemm6_body<PRESPLIT>(J, blockIdx.x, blockIdx.y, nkc, N, Ahi, Amid, Alo);
}

// ---------------------------------------------------------------------------
// [M,1024] @ [1024,1024] split6 GEMM (keys and memV): grid (U/128, M/64).
// (R16-proven single-output version — higher occupancy than fused kv.)
// ---------------------------------------------------------------------------
template<bool PRESPLIT>
__global__ __launch_bounds__(256) void gemm_keys(
    const float* __restrict__ A, const float* __restrict__ W,
    const ushortT* __restrict__ Wp, float* __restrict__ C)
{
    const int tid = threadIdx.x;
    const int lane = tid & 63;
    const int wave = tid >> 6;
    const int row0 = blockIdx.y * 64;
    const int nt0 = blockIdx.x * 8 + wave * 2;
    const int col0 = nt0 * 16 + (lane & 15);
    const int kfrag = (lane >> 4) * 8;

    __shared__ __align__(16) ushortT Ahi[2048];
    __shared__ __align__(16) ushortT Amid[2048];
    __shared__ __align__(16) ushortT Alo[2048];

    f32x4 acc[2][4] = {};
    const int arow = row0 + (tid >> 6) * 16 + (tid & 15);
    const int kgof = ((tid >> 4) & 3) * 8;
    const size_t ps = (size_t)U * U;

    for (int kc = 0; kc < 32; kc++) {
        const float* ar = A + (size_t)arow * U + kc * 32 + kgof;
        float av[8];
        *(float4*)(av)     = *(const float4*)(ar);
        *(float4*)(av + 4) = *(const float4*)(ar + 4);
        ushortT thi[8], tmi[8], tlo[8];
        #pragma unroll
        for (int i = 0; i < 8; i++) split3(av[i], thi[i], tmi[i], tlo[i]);
        ((uint4*)Ahi)[tid]  = *(const uint4*)thi;
        ((uint4*)Amid)[tid] = *(const uint4*)tmi;
        ((uint4*)Alo)[tid]  = *(const uint4*)tlo;

        bf16x8 bh[2], bm[2], bl[2];
        #pragma unroll
        for (int j = 0; j < 2; j++) {
            if constexpr (PRESPLIT) {
                size_t fi = (((size_t)(nt0 + j) * 32 + kc) * 64 + lane) * 8;
                bh[j] = *(const bf16x8*)(Wp + fi);
                bm[j] = *(const bf16x8*)(Wp + ps + fi);
                bl[j] = *(const bf16x8*)(Wp + 2 * ps + fi);
            } else {
                const float* wp = W + (size_t)(kc * 32 + kfrag) * U + col0 + j * 16;
                ushortT whi[8], wmi[8], wlo[8];
                #pragma unroll
                for (int i = 0; i < 8; i++)
                    split3(wp[(size_t)i * U], whi[i], wmi[i], wlo[i]);
                bh[j] = *(const bf16x8*)whi;
                bm[j] = *(const bf16x8*)wmi;
                bl[j] = *(const bf16x8*)wlo;
            }
        }

        __syncthreads();
        #pragma unroll
        for (int mi = 0; mi < 4; mi++) {
            bf16x8 ah = *(const bf16x8*)(Ahi  + (mi * 64 + lane) * 8);
            bf16x8 am = *(const bf16x8*)(Amid + (mi * 64 + lane) * 8);
            bf16x8 al = *(const bf16x8*)(Alo  + (mi * 64 + lane) * 8);
            #pragma unroll
            for (int j = 0; j < 2; j++) {
                acc[j][mi] = __builtin_amdgcn_mfma_f32_16x16x32_bf16(ah, bh[j], acc[j][mi], 0, 0, 0);
                acc[j][mi] = __builtin_amdgcn_mfma_f32_16x16x32_bf16(am, bh[j], acc[j][mi], 0, 0, 0);
                acc[j][mi] = __builtin_amdgcn_mfma_f32_16x16x32_bf16(ah, bm[j], acc[j][mi], 0, 0, 0);
                acc[j][mi] = __builtin_amdgcn_mfma_f32_16x16x32_bf16(am, bm[j], acc[j][mi], 0, 0, 0);
                acc[j][mi] = __builtin_amdgcn_mfma_f32_16x16x32_bf16(al, bh[j], acc[j][mi], 0, 0, 0);
                acc[j][mi] = __builtin_amdgcn_mfma_f32_16x16x32_bf16(ah, bl[j], acc[j][mi], 0, 0, 0);
            }
        }
        __syncthreads();
    }

    #pragma unroll
    for (int mi = 0; mi < 4; mi++) {
        #pragma unroll
        for (int r = 0; r < 4; r++) {
            int m = row0 + mi * 16 + (lane >> 4) * 4 + r;
            #pragma unroll
            for (int j = 0; j < 2; j++)
                C[(size_t)m * U + col0 + j * 16] = acc[j][mi][r];
        }
    }
}

// ---------------------------------------------------------------------------
// xe[t] = emb[x[:,t]] @ gk[0:256,:]   grid (U3/64, T)
// ---------------------------------------------------------------------------
template<bool PRESPLIT>
__global__ __launch_bounds__(256) void gemm_xe(
    const int* __restrict__ x, const float* __restrict__ emb,
    const float* __restrict__ gk, const ushortT* __restrict__ gkp,
    float* __restrict__ xe)
{
    const int tid = threadIdx.x;
    const int lane = tid & 63;
    const int wave = tid >> 6;
    const int t = blockIdx.y;
    const int ntile = blockIdx.x * 4 + wave;
    const int col = ntile * 16 + (lane & 15);
    const int kfrag = (lane >> 4) * 8;

    __shared__ __align__(16) ushortT Ahi[2048];
    __shared__ __align__(16) ushortT Amid[2048];
    __shared__ __align__(16) ushortT Alo[2048];

    f32x4 acc[4] = {};
    const int b = (tid >> 6) * 16 + (tid & 15);
    const int tok = x[b * T + t];
    const int kgof = ((tid >> 4) & 3) * 8;
    const size_t ps = (size_t)KXM * U3;

    for (int kc = 0; kc < E / 32; kc++) {
        const float* ar = emb + (size_t)tok * E + kc * 32 + kgof;
        float av[8];
        *(float4*)(av)     = *(const float4*)(ar);
        *(float4*)(av + 4) = *(const float4*)(ar + 4);
        ushortT thi[8], tmi[8], tlo[8];
        #pragma unroll
        for (int i = 0; i < 8; i++) split3(av[i], thi[i], tmi[i], tlo[i]);
        ((uint4*)Ahi)[tid]  = *(const uint4*)thi;
        ((uint4*)Amid)[tid] = *(const uint4*)tmi;
        ((uint4*)Alo)[tid]  = *(const uint4*)tlo;

        bf16x8 bh, bm, bl;
        if constexpr (PRESPLIT) {
            size_t fi = (((size_t)ntile * 40 + kc) * 64 + lane) * 8;   // gk KCtot=40
            bh = *(const bf16x8*)(gkp + fi);
            bm = *(const bf16x8*)(gkp + ps + fi);
            bl = *(const bf16x8*)(gkp + 2 * ps + fi);
        } else {
            const float* wp = gk + (size_t)(kc * 32 + kfrag) * U3 + col;
            ushortT whi[8], wmi[8], wlo[8];
            #pragma unroll
            for (int i = 0; i < 8; i++)
                split3(wp[(size_t)i * U3], whi[i], wmi[i], wlo[i]);
            bh = *(const bf16x8*)whi;
            bm = *(const bf16x8*)wmi;
            bl = *(const bf16x8*)wlo;
        }

        __syncthreads();
        #pragma unroll
        for (int mi = 0; mi < 4; mi++) {
            bf16x8 ah = *(const bf16x8*)(Ahi  + (mi * 64 + lane) * 8);
            bf16x8 am = *(const bf16x8*)(Amid + (mi * 64 + lane) * 8);
            bf16x8 al = *(const bf16x8*)(Alo  + (mi * 64 + lane) * 8);
            acc[mi] = __builtin_amdgcn_mfma_f32_16x16x32_bf16(ah, bh, acc[mi], 0, 0, 0);
            acc[mi] = __builtin_amdgcn_mfma_f32_16x16x32_bf16(am, bh, acc[mi], 0, 0, 0);
            acc[mi] = __builtin_amdgcn_mfma_f32_16x16x32_bf16(ah, bm, acc[mi], 0, 0, 0);
            acc[mi] = __builtin_amdgcn_mfma_f32_16x16x32_bf16(am, bm, acc[mi], 0, 0, 0);
            acc[mi] = __builtin_amdgcn_mfma_f32_16x16x32_bf16(al, bh, acc[mi], 0, 0, 0);
            acc[mi] = __builtin_amdgcn_mfma_f32_16x16x32_bf16(ah, bl, acc[mi], 0, 0, 0);
        }
        __syncthreads();
    }

    #pragma unroll
    for (int mi = 0; mi < 4; mi++) {
        #pragma unroll
        for (int r = 0; r < 4; r++) {
            int m = mi * 16 + (lane >> 4) * 4 + r;
            xe[((size_t)t * 64 + m) * U3 + col] = acc[mi][r];
        }
    }
}

// ---------------------------------------------------------------------------
// Batched fc GEMM (M64, bf16 A, XCD-pinned t-major) — R20-proven.
// ---------------------------------------------------------------------------
__global__ __launch_bounds__(256) void gemm_fcB(
    const ushortT* __restrict__ A, const ushortT* __restrict__ Wp,
    const float* __restrict__ bias, float* __restrict__ C)
{
    const int xcd = blockIdx.x & 7;
    const int rem = blockIdx.x >> 3;        // g*19 + t
    const int g = rem / T;
    const int tg = rem - g * T;
    const int strip = g * 8 + xcd;
    if (strip >= V / 128) return;

    const int tid = threadIdx.x;
    const int lane = tid & 63;
    const int wave = tid >> 6;
    const int nt0 = strip * 8 + wave * 2;
    const int col0 = nt0 * 16 + (lane & 15);

    __shared__ __align__(16) ushortT As[2][2048];

    f32x4 acc[2][4] = {};
    const int arow = (tid >> 6) * 16 + (tid & 15);
    const ushortT* At = A + (size_t)tg * 64 * U;
    float* Ct = C + (size_t)tg * V;
    const int kgof = ((tid >> 4) & 3) * 8;

    for (int it = 0; it < 16; it++) {
        #pragma unroll
        for (int c = 0; c < 2; c++) {
            const ushortT* ar = At + (size_t)arow * U + (it * 2 + c) * 32 + kgof;
            ((uint4*)As[c])[tid] = *(const uint4*)ar;
        }
        bf16x8 b[2][2];
        #pragma unroll
        for (int c = 0; c < 2; c++)
            #pragma unroll
            for (int j = 0; j < 2; j++)
                b[c][j] = *(const bf16x8*)(Wp +
                    (((size_t)(nt0 + j) * 32 + it * 2 + c) * 64 + lane) * 8);
        __syncthreads();
        #pragma unroll
        for (int c = 0; c < 2; c++) {
            #pragma unroll
            for (int mi = 0; mi < 4; mi++) {
                bf16x8 a = *(const bf16x8*)(As[c] + (mi * 64 + lane) * 8);
                #pragma unroll
                for (int j = 0; j < 2; j++)
                    acc[j][mi] = __builtin_amdgcn_mfma_f32_16x16x32_bf16(a, b[c][j], acc[j][mi], 0, 0, 0);
            }
        }
        __syncthreads();
    }

    #pragma unroll
    for (int j = 0; j < 2; j++) {
        const float bv = bias[col0 + j * 16];
        #pragma unroll
        for (int mi = 0; mi < 4; mi++) {
            #pragma unroll
            for (int r = 0; r < 4; r++) {
                int m = mi * 16 + (lane >> 4) * 4 + r;
                __builtin_nontemporal_store(acc[j][mi][r] + bv,
                    &Ct[(size_t)m * (T * V) + col0 + j * 16]);
            }
        }
    }
}

// ---------------------------------------------------------------------------
// GRU gates at full parallelism: grid B*U/256 = 256 blocks (R19-proven).
// ---------------------------------------------------------------------------
__global__ __launch_bounds__(256) void gates_k(
    const float* __restrict__ xe_t, const float* __restrict__ xm_part,
    const float* __restrict__ hm_part, const float* __restrict__ gb,
    float* __restrict__ h, int use_xm)
{
    int idx = blockIdx.x * 256 + threadIdx.x;   // B*U
    int b = idx >> 10, u = idx & (U - 1);
    float xv[3], hv[3];
    #pragma unroll
    for (int g = 0; g < 3; g++) {
        int j = g * U + u;
        float xs = xe_t[(size_t)b * U3 + j] + gb[j];
        float hsum = gb[U3 + j];
        if (use_xm) {
            #pragma unroll
            for (int p = 0; p < 8; p++)
                xs += xm_part[((size_t)p * 64 + b) * U3 + j];
        }
        #pragma unroll
        for (int p = 0; p < 8; p++)
            hsum += hm_part[((size_t)p * 64 + b) * U3 + j];
        xv[g] = xs; hv[g] = hsum;
    }
    float z = 1.f / (1.f + expf(-(xv[0] + hv[0])));
    float r = 1.f / (1.f + expf(-(xv[1] + hv[1])));
    float hh = tanhf(xv[2] + r * hv[2]);
    h[idx] = z * h[idx] + (1.f - z) * hh;
}

// ---------------------------------------------------------------------------
// Co-launched scores (1280 blocks, wave per (b,s)) + ah = h@Wtop (128 blocks).
// (R19-proven.)
// ---------------------------------------------------------------------------
template<bool PRESPLIT>
__global__ __launch_bounds__(256) void sc_ah(
    const float* __restrict__ h, const float* __restrict__ keys,
    float* __restrict__ scores,
    const float* __restrict__ Wtop, const ushortT* __restrict__ wtpp,
    float* __restrict__ ah_part)
{
    __shared__ __align__(16) ushortT Ahi[2048];
    __shared__ __align__(16) ushortT Amid[2048];
    __shared__ __align__(16) ushortT Alo[2048];

    const int bid = blockIdx.x;
    if (bid < B * S / 4) {
        int gw = bid * 4 + (threadIdx.x >> 6);
        int lane = threadIdx.x & 63;
        int b = gw / S, s = gw - b * S;
        const float* kr = keys + ((size_t)b * S + s) * U;
        const float* hr = h + (size_t)b * U;
        float acc = 0.f;
        #pragma unroll
        for (int c = 0; c < 4; c++) {
            int off = c * 256 + lane * 4;
            float4 kv = *(const float4*)(kr + off);
            float4 hv = *(const float4*)(hr + off);
            acc += kv.x * hv.x + kv.y * hv.y + kv.z * hv.z + kv.w * hv.w;
        }
        #pragma unroll
        for (int off = 32; off > 0; off >>= 1) acc += __shfl_down(acc, off);
        if (lane == 0) scores[gw] = acc;
    } else {
        int r = bid - B * S / 4;       // 0..127: 16 x-tiles x 8 ks
        GemmJob job = { h, Wtop, wtpp, (size_t)U * U, 0, 32, ah_part, U };
        gemm6_body<PRESPLIT>(job, r & 15, r >> 4, 4, U, Ahi, Amid, Alo);
    }
}

// ---------------------------------------------------------------------------
// pnmv + inline softmax: attnv = sum8(ah_part) + softmax(scores)@memV.
// Writes fp32 (xm GEMM) and bf16 (fcB; bit-identical to old inline f2bf).
// ---------------------------------------------------------------------------
__global__ __launch_bounds__(256) void pnmv_sm(
    const float* __restrict__ ah_part, const float* __restrict__ scores,
    const float* __restrict__ memV, float* __restrict__ dst,
    ushortT* __restrict__ dst_bf)
{
    const int b = blockIdx.x;
    const int u = blockIdx.y * 256 + threadIdx.x;
    __shared__ float p[S];
    __shared__ float pl[S];
    if (threadIdx.x < S) p[threadIdx.x] = scores[b * S + threadIdx.x];
    __syncthreads();
    float m = -1e30f;
    #pragma unroll 8
    for (int s = 0; s < S; s++) m = fmaxf(m, p[s]);
    float sum = 0.f;
    #pragma unroll 8
    for (int s = 0; s < S; s++) sum += expf(p[s] - m);
    if (threadIdx.x < S) pl[threadIdx.x] = expf(p[threadIdx.x] - m) / sum;
    __syncthreads();
    float acc = 0.f;
    #pragma unroll
    for (int pp = 0; pp < 8; pp++)
        acc += ah_part[((size_t)pp * 64 + b) * U + u];
    #pragma unroll 8
    for (int s = 0; s < S; s++)
        acc += pl[s] * memV[((size_t)b * S + s) * U + u];
    dst[(size_t)b * U + u] = acc;
    dst_bf[(size_t)b * U + u] = f2bf(acc);
}

// ---------------------------------------------------------------------------
extern "C" void kernel_launch(void* const* d_in, const int* in_sizes, int n_in,
                              void* d_out, int out_size, void* d_ws, size_t ws_size,
                              hipStream_t stream)
{
    const int*   x      = (const int*)  d_in[0];
    const float* enc    = (const float*)d_in[1];
    const float* memory = (const float*)d_in[2];
    const float* emb    = (const float*)d_in[3];
    const float* gk     = (const float*)d_in[4];
    const float* grk    = (const float*)d_in[5];
    const float* gb     = (const float*)d_in[6];
    const float* memW   = (const float*)d_in[7];
    const float* attnW  = (const float*)d_in[8];
    const float* fcW    = (const float*)d_in[9];
    const float* fcb    = (const float*)d_in[10];
    float* out = (float*)d_out;

    const float* Wtop = attnW;
    const float* Wbot = attnW + (size_t)U * U;

    char* p = (char*)d_ws;
    auto alloc = [&](size_t bytes) { char* r = p; p += (bytes + 255) & ~(size_t)255; return r; };
    ushortT* fcWp      = (ushortT*)alloc((size_t)U * V * 2);
    float*   keys      = (float*)  alloc((size_t)B * S * U * 4);
    float*   memV      = (float*)  alloc((size_t)B * S * U * 4);
    float*   xe        = (float*)  alloc((size_t)T * B * U3 * 4);
    float*   xm_part   = (float*)  alloc((size_t)8 * B * U3 * 4);
    float*   hm_part   = (float*)  alloc((size_t)8 * B * U3 * 4);
    float*   ah_part   = (float*)  alloc((size_t)8 * B * U * 4);
    float*   h         = (float*)  alloc((size_t)B * U * 4);
    float*   attnv_all = (float*)  alloc((size_t)T * B * U * 4);
    ushortT* attnv_bf  = (ushortT*)alloc((size_t)T * B * U * 2);
    float*   scores    = (float*)  alloc((size_t)B * S * 4);
    ushortT* gkp       = (ushortT*)alloc((size_t)KXM * U3 * 2 * 3);
    ushortT* grkp      = (ushortT*)alloc((size_t)U * U3 * 2 * 3);
    ushortT* wtpp      = (ushortT*)alloc((size_t)U * U * 2 * 3);
    ushortT* wbpp      = (ushortT*)alloc((size_t)U * U * 2 * 3);
    ushortT* mwp       = (ushortT*)alloc((size_t)U * U * 2 * 3);
    const bool PS = (size_t)(p - (char*)d_ws) <= ws_size;

    dim3 blk(256);

    if (PS) {
        PackJob j0 = { gk,   gkp,  U3, KXM, 0 };
        PackJob j1 = { grk,  grkp, U3, U,   1920 };
        PackJob j2 = { Wtop, wtpp, U,  U,   1920 + 1536 };
        PackJob j3 = { Wbot, wbpp, U,  U,   1920 + 1536 + 512 };
        PackJob j4 = { memW, mwp,  U,  U,   1920 + 1536 + 512 + 512 };
        pack_w3_all<<<1920 + 1536 + 512 + 512 + 512, blk, 0, stream>>>(j0, j1, j2, j3, j4);
    }
    pack_w<<<(size_t)U * V / 8 / 256, blk, 0, stream>>>(fcW, fcWp, V, U);
    (void)hipMemcpyAsync(h, enc, (size_t)B * U * sizeof(float),
                         hipMemcpyDeviceToDevice, stream);

    if (PS) gemm_xe<true><<<dim3(U3 / 64, T), blk, 0, stream>>>(x, emb, gk, gkp, xe);
    else    gemm_xe<false><<<dim3(U3 / 64, T), blk, 0, stream>>>(x, emb, gk, gkp, xe);

    // keys and memV as two independent high-occupancy GEMMs (R16-proven)
    if (PS) gemm_keys<true><<<dim3(U / 128, B * S / 64), blk, 0, stream>>>(memory, memW, mwp, keys);
    else    gemm_keys<false><<<dim3(U / 128, B * S / 64), blk, 0, stream>>>(memory, memW, mwp, keys);

    if (PS) gemm_keys<true><<<dim3(U / 128, B * S / 64), blk, 0, stream>>>(memory, Wbot, wbpp, memV);
    else    gemm_keys<false><<<dim3(U / 128, B * S / 64), blk, 0, stream>>>(memory, Wbot, wbpp, memV);

    GemmJob job_hm = { h, grk, grkp, (size_t)U * U3, 0, 32, hm_part, U };

    for (int t = 0; t < T; t++) {
        GemmJob job_xm = { attnv_all + (size_t)(t - 1) * B * U, gk, gkp,
                           (size_t)KXM * U3, 8, 40, xm_part, U };
        // 1) hm (+xm) — R14-proven ks=8, nkc=4
        dim3 g1(U3 / 64, 8, t > 0 ? 2 : 1);
        if (PS) gemm6_ks2<true><<<g1, blk, 0, stream>>>(job_hm, job_xm, U3, 4);
        else    gemm6_ks2<false><<<g1, blk, 0, stream>>>(job_hm, job_xm, U3, 4);
        // 2) gates at 256 blocks
        gates_k<<<B * U / 256, blk, 0, stream>>>(
            xe + (size_t)t * B * U3, xm_part, hm_part, gb, h, t > 0 ? 1 : 0);
        // 3) scores (1280) || ah = h@Wtop (128)
        if (PS) sc_ah<true><<<B * S / 4 + 128, blk, 0, stream>>>(
            h, keys, scores, Wtop, wtpp, ah_part);
        else    sc_ah<false><<<B * S / 4 + 128, blk, 0, stream>>>(
            h, keys, scores, Wtop, wtpp, ah_part);
        // 4) attnv = sum8(ah) + softmax(scores)@memV  (fp32 + bf16 copies)
        pnmv_sm<<<dim3(B, U / 256), blk, 0, stream>>>(
            ah_part, scores, memV, attnv_all + (size_t)t * B * U,
            attnv_bf + (size_t)t * B * U);
    }

    // all logits at once: bf16 A [T*64, U] @ packed fcW + fcb (M64, XCD-pinned)
    gemm_fcB<<<32 * T * 8, blk, 0, stream>>>(attnv_bf, fcWp, fcb, out);
}